// Round 7
// baseline (199.876 us; speedup 1.0000x reference)
//
#include <hip/hip_runtime.h>

#define C_ 64
#define H_ 128
#define W_ 128
#define B_ 8
#define HW_ (H_*W_)
#define NPIX (B_*HW_)

typedef _Float16 half8 __attribute__((ext_vector_type(8)));
typedef _Float16 half4 __attribute__((ext_vector_type(4)));
typedef float floatx4 __attribute__((ext_vector_type(4)));

// ---------------------------------------------------------------------------
// Prep (round-7): build the prologue GEMM weight table wOffA [32][384] f16:
//   rows  0..5  off_h  | cols 0..191  = k*64+c of w_off_h[o][c][0][k]
//   rows  6..8  mask_h | cols 0..191
//   rows  9..14 off_v  | cols 192..383 = 192 + k*64+c of w_off_v
//   rows 15..17 mask_v | cols 192..383
//   all other slots zero (block-structured: h-group only contracts against
//   horizontal-shift columns, v-group against vertical).
// Deform weights wF16_h/v keep the K' = k*64+c layout (matches valT writes).
// ---------------------------------------------------------------------------
__global__ __launch_bounds__(256) void prep_kernel(
    const float* __restrict__ w_off_h, const float* __restrict__ w_mask_h,
    const float* __restrict__ w_off_v, const float* __restrict__ w_mask_v,
    const float* __restrict__ w_h, const float* __restrict__ w_v,
    _Float16* __restrict__ wOffA, _Float16* __restrict__ wF16_h,
    _Float16* __restrict__ wF16_v)
{
    int gid = blockIdx.x * 256 + threadIdx.x;
    if (gid < 32 * 384) {
        int o = gid / 384, col = gid - o * 384;
        int half_ = col / 192, rem = col - half_ * 192;
        int kk = rem >> 6, cc = rem & 63;
        int src = cc * 3 + kk;
        float v = 0.f;
        if (half_ == 0) {
            if (o < 6)                 v = w_off_h [o * 192 + src];
            else if (o < 9)            v = w_mask_h[(o - 6) * 192 + src];
        } else {
            if (o >= 9 && o < 15)      v = w_off_v [(o - 9) * 192 + src];
            else if (o >= 15 && o < 18) v = w_mask_v[(o - 15) * 192 + src];
        }
        wOffA[gid] = (_Float16)v;
    } else if (gid < 12288 + 24576) {
        int i = gid - 12288;
        if (i < 12288) {
            int o = i / 192, rem = i - o * 192;
            int c = rem / 3, k = rem - 3 * c;
            wF16_h[o * 192 + k * 64 + c] = (_Float16)w_h[i];
        } else {
            i -= 12288;
            int o = i / 192, rem = i - o * 192;
            int c = rem / 3, k = rem - 3 * c;
            wF16_v[o * 192 + k * 64 + c] = (_Float16)w_v[i];
        }
    }
}

// ---------------------------------------------------------------------------
// Transpose x: NCHW f32 -> NHWC f16 ([n][pix][c]).
// ---------------------------------------------------------------------------
__global__ __launch_bounds__(256, 8) void transpose_kernel(
    const float* __restrict__ x, _Float16* __restrict__ xT)
{
    __shared__ _Float16 tile[64][66];
    int lane = threadIdx.x & 63;
    int wv   = threadIdx.x >> 6;
    int bid = blockIdx.x;
    int n = bid & 7;          // XCD-pinned, same mapping as consumers
    int m = bid >> 3;
    const float* xs = x + (size_t)n * C_ * HW_ + (size_t)m * 64;
    #pragma unroll
    for (int cc = 0; cc < 16; ++cc) {
        int c = wv * 16 + cc;
        tile[c][lane] = (_Float16)xs[(size_t)c * HW_ + lane];
    }
    __syncthreads();
    _Float16* xd = xT + ((size_t)n * HW_ + (size_t)m * 64) * 64;
    #pragma unroll
    for (int pp = 0; pp < 16; ++pp) {
        int p = wv * 16 + pp;
        xd[(size_t)p * 64 + lane] = tile[lane][p];
    }
}

// Per-(pixel,tap) setup -> LDS (threads t < 192). 2x2 tile base clamped
// in-image; corner weights routed to relative slots (round-6 verified).
#define TAP_SETUP_192(OFFP, MASKP, KYO, KXO)                                  \
    {                                                                         \
        int t = threadIdx.x;                                                  \
        if (t < 192) {                                                        \
            int p = t / 3, k = t - 3 * p;                                     \
            int pixp = m * 64 + p;                                            \
            float dy = (OFFP##_DY);                                           \
            float dx = (OFFP##_DX);                                           \
            float mm = (MASKP);                                               \
            float fi = (float)(pixp >> 7), fj = (float)(pixp & (W_ - 1));     \
            float py = fi + (float)(KYO) + dy;                                \
            float px = fj + (float)(KXO) + dx;                                \
            float y0f = floorf(py), x0f = floorf(px);                         \
            float wy = py - y0f, wx = px - x0f;                               \
            int y0 = (int)y0f, x0 = (int)x0f;                                 \
            int y1 = y0 + 1, x1 = x0 + 1;                                     \
            bool vy0 = (y0 >= 0) && (y0 < H_);                                \
            bool vy1 = (y1 >= 0) && (y1 < H_);                                \
            bool vx0 = (x0 >= 0) && (x0 < W_);                                \
            bool vx1 = (x1 >= 0) && (x1 < W_);                                \
            float wy1 = 1.f - wy, wx1 = 1.f - wx;                             \
            float w00 = (vy0 && vx0) ? wy1 * wx1 * mm : 0.f;                  \
            float w01 = (vy0 && vx1) ? wy1 * wx  * mm : 0.f;                  \
            float w10 = (vy1 && vx0) ? wy  * wx1 * mm : 0.f;                  \
            float w11 = (vy1 && vx1) ? wy  * wx  * mm : 0.f;                  \
            int y0c = min(max(y0, 0), H_ - 1), y1c = min(max(y1, 0), H_ - 1); \
            int x0c = min(max(x0, 0), W_ - 1), x1c = min(max(x1, 0), W_ - 1); \
            int yb = min(max(y0, 0), H_ - 2),  xb = min(max(x0, 0), W_ - 2);  \
            int r0 = y0c - yb, r1 = y1c - yb;   /* in {0,1} */                \
            int cA = x0c - xb, cB = x1c - xb;   /* in {0,1} */                \
            floatx4 w;                                                        \
            w[0] = ((r0==0)&&(cA==0)?w00:0.f) + ((r0==0)&&(cB==0)?w01:0.f)    \
                 + ((r1==0)&&(cA==0)?w10:0.f) + ((r1==0)&&(cB==0)?w11:0.f);   \
            w[1] = ((r0==0)&&(cA==1)?w00:0.f) + ((r0==0)&&(cB==1)?w01:0.f)    \
                 + ((r1==0)&&(cA==1)?w10:0.f) + ((r1==0)&&(cB==1)?w11:0.f);   \
            w[2] = ((r0==1)&&(cA==0)?w00:0.f) + ((r0==1)&&(cB==0)?w01:0.f)    \
                 + ((r1==1)&&(cA==0)?w10:0.f) + ((r1==1)&&(cB==0)?w11:0.f);   \
            w[3] = ((r0==1)&&(cA==1)?w00:0.f) + ((r0==1)&&(cB==1)?w01:0.f)    \
                 + ((r1==1)&&(cA==1)?w10:0.f) + ((r1==1)&&(cB==1)?w11:0.f);   \
            tapI[t] = (yb * W_ + xb) * 64;                                    \
            tapW[t] = w;                                                      \
        }                                                                     \
    }

// NHWC gather + MFMA over two 32-pixel halves (round-6 verified).
#define GATHER_MFMA_BODY(ST)                                                  \
    int col = lane & 15;                                                      \
    floatx4 accT[4];                                                          \
    _Pragma("unroll")                                                         \
    for (int T = 0; T < 4; ++T) accT[T] = floatx4{0.f, 0.f, 0.f, 0.f};        \
    _Pragma("unroll")                                                         \
    for (int hf = 0; hf < 2; ++hf) {                                          \
        _Pragma("unroll")                                                     \
        for (int q = 0; q < 8; ++q) {                                         \
            int r = wv * 8 + q;                                               \
            int p = hf * 32 + r;                                              \
            _Pragma("unroll")                                                 \
            for (int k = 0; k < 3; ++k) {                                     \
                int ex = __builtin_amdgcn_readfirstlane(tapI[p * 3 + k]);     \
                floatx4 w = tapW[p * 3 + k];                                  \
                const _Float16* cb = (ST) + ex;                               \
                float v00 = (float)cb[lane];                                  \
                float v01 = (float)cb[lane + 64];                             \
                float v10 = (float)cb[lane + 64 * W_];                        \
                float v11 = (float)cb[lane + 64 * W_ + 64];                   \
                float v = fmaf(w[0], v00, fmaf(w[1], v01,                     \
                          fmaf(w[2], v10, w[3] * v11)));                      \
                valT[r][k * 64 + lane] = (_Float16)v;                         \
            }                                                                 \
        }                                                                     \
        __syncthreads();                                                      \
        const _Float16* wpA = wF16 + (size_t)(c0 + (lane & 15)) * 192         \
                            + ((lane >> 4) << 3);                             \
        half8 A0 = *((const half8*)(wpA +   0));                              \
        half8 A1 = *((const half8*)(wpA +  32));                              \
        half8 A2 = *((const half8*)(wpA +  64));                              \
        half8 A3 = *((const half8*)(wpA +  96));                              \
        half8 A4 = *((const half8*)(wpA + 128));                              \
        half8 A5 = *((const half8*)(wpA + 160));                              \
        _Pragma("unroll")                                                     \
        for (int tt = 0; tt < 2; ++tt) {                                      \
            int T = hf * 2 + tt;                                              \
            const _Float16* bp = &valT[tt * 16 + col][(lane >> 4) << 3];      \
            floatx4 acc = accT[T];                                            \
            acc = __builtin_amdgcn_mfma_f32_16x16x32_f16(A0, *((const half8*)(bp +   0)), acc, 0, 0, 0); \
            acc = __builtin_amdgcn_mfma_f32_16x16x32_f16(A1, *((const half8*)(bp +  32)), acc, 0, 0, 0); \
            acc = __builtin_amdgcn_mfma_f32_16x16x32_f16(A2, *((const half8*)(bp +  64)), acc, 0, 0, 0); \
            acc = __builtin_amdgcn_mfma_f32_16x16x32_f16(A3, *((const half8*)(bp +  96)), acc, 0, 0, 0); \
            acc = __builtin_amdgcn_mfma_f32_16x16x32_f16(A4, *((const half8*)(bp + 128)), acc, 0, 0, 0); \
            acc = __builtin_amdgcn_mfma_f32_16x16x32_f16(A5, *((const half8*)(bp + 160)), acc, 0, 0, 0); \
            accT[T] = acc;                                                    \
        }                                                                     \
        if (hf == 0) __syncthreads();                                         \
    }

// ---------------------------------------------------------------------------
// Fused horizontal pass, round-7: offset/mask prologue is now an MFMA GEMM
// over K=384 (h-shift cols 0..191, v-shift cols 192..383) reading xT NHWC —
// coalesced wave-uniform loads, wave-private LDS staging (no barriers), 24
// MFMAs replace ~864 VALU fmaf + 80 scattered loads + cross-wave reduce.
// smem: Bbuf [4][16][72] f16 @0 (9216 B, P1, overlaps dead valT) |
//       valT [32][200] @0 (12800 B, P2) | tapI @12800 | tapW @13568 |
//       redC [9][64] f32 @16640 (P1 scatter -> tap_setup). Total 18944 B.
// ---------------------------------------------------------------------------
__global__ __launch_bounds__(256, 8) void deform_h_kernel(
    const _Float16* __restrict__ xT, const _Float16* __restrict__ wOffA,
    const float* __restrict__ b_off_h, const float* __restrict__ b_mask_h,
    const float* __restrict__ b_off_v, const float* __restrict__ b_mask_v,
    const _Float16* __restrict__ wF16, const float* __restrict__ bias,
    float* __restrict__ off_v, float* __restrict__ mask_v,
    _Float16* __restrict__ x_hT)
{
    __shared__ __align__(16) char smem[18944];
    _Float16 (*valT)[200] = reinterpret_cast<_Float16(*)[200]>(smem);
    _Float16 (*Bbuf)[16][72] = reinterpret_cast<_Float16(*)[16][72]>(smem);
    int*     tapI = reinterpret_cast<int*>(smem + 12800);     // 768 B
    floatx4* tapW = reinterpret_cast<floatx4*>(smem + 13568); // 3072 B
    float (*redC)[64] = reinterpret_cast<float(*)[64]>(smem + 16640); // 2304 B

    int lane = threadIdx.x & 63;
    int wv   = threadIdx.x >> 6;
    int c0 = __builtin_amdgcn_readfirstlane(wv << 4);   // SGPR slice base

    int bid = blockIdx.x;
    int n   = bid & 7;
    int m   = bid >> 3;

    const _Float16* sT = xT + (size_t)n * (HW_ * 64);

    // ---- prologue GEMM: C[18 out][64 pix] over K=384; wave owns 16 pixels.
    // Speculative OOB addresses (vld false) stay inside allocated ws:
    // xT is preceded by mask_v and followed by x_hT.
    int pb = m * 64 + wv * 16;
    floatx4 accP0 = {0.f, 0.f, 0.f, 0.f};
    floatx4 accP1 = {0.f, 0.f, 0.f, 0.f};
    #pragma unroll
    for (int ck = 0; ck < 6; ++ck) {            // 3 h-shifts, then 3 v-shifts
        int kk = (ck < 3) ? ck : ck - 3;
        #pragma unroll
        for (int rr = 0; rr < 16; ++rr) {
            int p = pb + rr;
            bool vld;
            int ad;
            if (ck < 3) { vld = (unsigned)((p & (W_ - 1)) + kk - 1) < W_; ad = p + (kk - 1); }
            else        { vld = (unsigned)((p >> 7)       + kk - 1) < H_; ad = p + (kk - 1) * W_; }
            _Float16 v = vld ? sT[(size_t)ad * 64 + lane] : (_Float16)0.f;
            Bbuf[wv][rr][lane] = v;             // contiguous 128-B wave store
        }
        #pragma unroll
        for (int s = 0; s < 2; ++s) {
            half8 Bf = *((const half8*)&Bbuf[wv][lane & 15][s * 32 + ((lane >> 4) << 3)]);
            const _Float16* wa = wOffA + (size_t)(lane & 15) * 384
                               + ck * 64 + s * 32 + ((lane >> 4) << 3);
            half8 A0 = *((const half8*)(wa));             // rows 0..15
            half8 A1 = *((const half8*)(wa + 16 * 384));  // rows 16..31
            accP0 = __builtin_amdgcn_mfma_f32_16x16x32_f16(A0, Bf, accP0, 0, 0, 0);
            accP1 = __builtin_amdgcn_mfma_f32_16x16x32_f16(A1, Bf, accP1, 0, 0, 0);
        }
    }

    // ---- scatter: h-group -> redC (consumed by tap_setup), v-group -> ws ----
    int pl = wv * 16 + (lane & 15);     // block-local pixel
    int pg = m * 64 + pl;               // image pixel
    #pragma unroll
    for (int e = 0; e < 4; ++e) {
        int o = ((lane >> 4) << 2) + e;
        float vv = accP0[e];
        if (o < 6) {
            redC[o][pl] = vv + b_off_h[o];
        } else if (o < 9) {
            redC[o][pl] = 1.f / (1.f + __expf(-(vv + b_mask_h[o - 6])));
        } else if (o < 15) {
            off_v[((size_t)n * 6 + (o - 9)) * HW_ + pg] = vv + b_off_v[o - 9];
        } else {   // o == 15
            mask_v[((size_t)n * 3 + 0) * HW_ + pg] =
                1.f / (1.f + __expf(-(vv + b_mask_v[0])));
        }
    }
    if ((lane >> 4) == 0) {             // tile1 rows 0,1 = outputs 16,17
        #pragma unroll
        for (int e = 0; e < 2; ++e) {
            float vv = accP1[e];
            mask_v[((size_t)n * 3 + 1 + e) * HW_ + pg] =
                1.f / (1.f + __expf(-(vv + b_mask_v[1 + e])));
        }
    }
    __syncthreads();

    // ---- tap setup (horizontal: kyo=0, kxo=k-1) from redC ----
#define H_DY redC[2*k    ][p]
#define H_DX redC[2*k + 1][p]
    TAP_SETUP_192(H, redC[6 + k][p], 0, (k - 1))
#undef H_DY
#undef H_DX
    __syncthreads();   // taps visible; Bbuf dead -> valT may overwrite

    GATHER_MFMA_BODY(sT)

    // ---- epilogue: NHWC f16 store, one half4 per tile ----
    int orow = c0 + ((lane >> 4) << 2);
    floatx4 bv = *((const floatx4*)&bias[orow]);
    _Float16* hb = x_hT + ((size_t)n * HW_ + (size_t)m * 64) * 64 + orow;
    #pragma unroll
    for (int T = 0; T < 4; ++T) {
        half4 o;
        o[0] = (_Float16)(accT[T][0] + bv[0]);
        o[1] = (_Float16)(accT[T][1] + bv[1]);
        o[2] = (_Float16)(accT[T][2] + bv[2]);
        o[3] = (_Float16)(accT[T][3] + bv[3]);
        *((half4*)(hb + (size_t)(T * 16 + col) * 64)) = o;
    }
}

// ---------------------------------------------------------------------------
// Vertical pass (round-6 structure, unchanged).
// ---------------------------------------------------------------------------
__global__ __launch_bounds__(256, 8) void deform_v_kernel(
    const _Float16* __restrict__ srcT, const float* __restrict__ off,
    const float* __restrict__ mask, const _Float16* __restrict__ wF16,
    const float* __restrict__ bias, float* __restrict__ out)
{
    __shared__ __align__(16) char smem[16640];
    _Float16 (*valT)[200] = reinterpret_cast<_Float16(*)[200]>(smem);
    int*     tapI = reinterpret_cast<int*>(smem + 12800);     // 768 B
    floatx4* tapW = reinterpret_cast<floatx4*>(smem + 13568); // 3072 B

    int lane = threadIdx.x & 63;
    int wv   = threadIdx.x >> 6;
    int c0 = __builtin_amdgcn_readfirstlane(wv << 4);

    int bid = blockIdx.x;
    int n   = bid & 7;
    int m   = bid >> 3;

#define V_DY off[(((size_t)n * 3 + k) * 2 + 0) * HW_ + pixp]
#define V_DX off[(((size_t)n * 3 + k) * 2 + 1) * HW_ + pixp]
    TAP_SETUP_192(V, mask[((size_t)n * 3 + k) * HW_ + pixp], (k - 1), 0)
#undef V_DY
#undef V_DX
    __syncthreads();

    const _Float16* sT = srcT + (size_t)n * (HW_ * 64);
    GATHER_MFMA_BODY(sT)

    // ---- epilogue: out is NCHW f32 (reference layout), nt-stores ----
    int orow = c0 + ((lane >> 4) << 2);
    floatx4 bv = *((const floatx4*)&bias[orow]);
    float* ob = out + ((size_t)n * C_ + orow) * HW_ + m * 64 + col;
    #pragma unroll
    for (int T = 0; T < 4; ++T) {
        __builtin_nontemporal_store(accT[T][0] + bv[0], &ob[T * 16 + (size_t)0 * HW_]);
        __builtin_nontemporal_store(accT[T][1] + bv[1], &ob[T * 16 + (size_t)1 * HW_]);
        __builtin_nontemporal_store(accT[T][2] + bv[2], &ob[T * 16 + (size_t)2 * HW_]);
        __builtin_nontemporal_store(accT[T][3] + bv[3], &ob[T * 16 + (size_t)3 * HW_]);
    }
}

// ---------------------------------------------------------------------------
extern "C" void kernel_launch(void* const* d_in, const int* in_sizes, int n_in,
                              void* d_out, int out_size, void* d_ws, size_t ws_size,
                              hipStream_t stream)
{
    const float* x        = (const float*)d_in[0];
    const float* w_off_h  = (const float*)d_in[1];
    const float* b_off_h  = (const float*)d_in[2];
    const float* w_mask_h = (const float*)d_in[3];
    const float* b_mask_h = (const float*)d_in[4];
    const float* w_off_v  = (const float*)d_in[5];
    const float* b_off_v  = (const float*)d_in[6];
    const float* w_mask_v = (const float*)d_in[7];
    const float* b_mask_v = (const float*)d_in[8];
    const float* w_h      = (const float*)d_in[9];
    const float* b_h      = (const float*)d_in[10];
    const float* w_v      = (const float*)d_in[11];
    const float* b_v      = (const float*)d_in[12];

    // ws: f32 region then f16 region; ~38.2 MB. xT is preceded (mask_v) and
    // followed (x_hT) by allocated regions so prologue speculative OOB
    // addresses (never consumed: vld-selected to 0) stay in bounds.
    float* ws      = (float*)d_ws;
    float* off_v   = ws;                    // 786432 f32
    float* mask_v  = off_v  + 786432;       // 393216 f32
    _Float16* xT     = (_Float16*)(mask_v + 393216); // 8388608 f16 (x NHWC)
    _Float16* x_hT   = xT + 8388608;                 // 8388608 f16 (x_h NHWC)
    _Float16* wOffA  = x_hT + 8388608;               // 12288 f16 [32][384]
    _Float16* wF16_h = wOffA + 12288;                // 12288 f16
    _Float16* wF16_v = wF16_h + 12288;               // 12288 f16

    prep_kernel<<<144, 256, 0, stream>>>(
        w_off_h, w_mask_h, w_off_v, w_mask_v, w_h, w_v,
        wOffA, wF16_h, wF16_v);

    dim3 grid(NPIX / 64), block(256);
    transpose_kernel<<<grid, block, 0, stream>>>(x, xT);

    deform_h_kernel<<<grid, block, 0, stream>>>(
        xT, wOffA, b_off_h, b_mask_h, b_off_v, b_mask_v,
        wF16_h, b_h, off_v, mask_v, x_hT);

    deform_v_kernel<<<grid, block, 0, stream>>>(
        x_hT, off_v, mask_v, wF16_v, b_v, (float*)d_out);
}

// Round 8
// 190.272 us; speedup vs baseline: 1.0505x; 1.0505x over previous
//
#include <hip/hip_runtime.h>

#define C_ 64
#define H_ 128
#define W_ 128
#define B_ 8
#define HW_ (H_*W_)
#define NPIX (B_*HW_)

typedef _Float16 half8 __attribute__((ext_vector_type(8)));
typedef _Float16 half4 __attribute__((ext_vector_type(4)));
typedef float floatx4 __attribute__((ext_vector_type(4)));

// ---------------------------------------------------------------------------
// Setup (round-8): ONE kernel = weight prep (blocks 0..109) + NCHW->NHWC f16
// transpose (all 2048 blocks). Saves one launch (~55-65 us of the pipeline is
// fixed overhead; 4 launches -> 3).
//   wOffAll[c][56] f32: packed offset/mask weights (wave-uniform s_loads).
//   wF16_h/v: deform weights, K' = k*64 + c layout (matches valT writes).
// ---------------------------------------------------------------------------
__global__ __launch_bounds__(256, 8) void setup_kernel(
    const float* __restrict__ x, _Float16* __restrict__ xT,
    const float* __restrict__ w_off_h, const float* __restrict__ w_mask_h,
    const float* __restrict__ w_off_v, const float* __restrict__ w_mask_v,
    const float* __restrict__ w_h, const float* __restrict__ w_v,
    float* __restrict__ wOffAll, _Float16* __restrict__ wF16_h,
    _Float16* __restrict__ wF16_v)
{
    // ---- weight prep: first 110 blocks ----
    int gid = blockIdx.x * 256 + threadIdx.x;
    if (gid < 64 * 56) {
        int c = gid / 56, idx = gid - 56 * c;
        float v = 0.f;
        if (idx < 18)      v = w_off_h [((idx      ) / 3) * 192 + c * 3 + (idx      ) % 3];
        else if (idx < 27) v = w_mask_h[((idx - 18) / 3) * 192 + c * 3 + (idx - 18) % 3];
        else if (idx < 45) v = w_off_v [((idx - 27) / 3) * 192 + c * 3 + (idx - 27) % 3];
        else if (idx < 54) v = w_mask_v[((idx - 45) / 3) * 192 + c * 3 + (idx - 45) % 3];
        wOffAll[c * 56 + idx] = v;
    } else if (gid < 3584 + 24576) {
        int i = gid - 3584;
        if (i < 12288) {
            int o = i / 192, rem = i - o * 192;
            int c = rem / 3, k = rem - 3 * c;
            wF16_h[o * 192 + k * 64 + c] = (_Float16)w_h[i];
        } else {
            i -= 12288;
            int o = i / 192, rem = i - o * 192;
            int c = rem / 3, k = rem - 3 * c;
            wF16_v[o * 192 + k * 64 + c] = (_Float16)w_v[i];
        }
    }

    // ---- transpose: all blocks; LDS-staged, [64][66] pad -> conflict-free ----
    __shared__ _Float16 tile[64][66];
    int lane = threadIdx.x & 63;
    int wv   = threadIdx.x >> 6;
    int bid = blockIdx.x;
    int n = bid & 7;          // XCD-pinned, same mapping as consumers
    int m = bid >> 3;
    const float* xs = x + (size_t)n * C_ * HW_ + (size_t)m * 64;
    #pragma unroll
    for (int cc = 0; cc < 16; ++cc) {
        int c = wv * 16 + cc;
        tile[c][lane] = (_Float16)xs[(size_t)c * HW_ + lane];
    }
    __syncthreads();
    _Float16* xd = xT + ((size_t)n * HW_ + (size_t)m * 64) * 64;
    #pragma unroll
    for (int pp = 0; pp < 16; ++pp) {
        int p = wv * 16 + pp;
        xd[(size_t)p * 64 + lane] = tile[lane][p];
    }
}

// XCD-aware swizzle: one image (n) pinned to XCD n (bid&7).
#define SWIZZLE_NP()                        \
    int bid = blockIdx.x;                   \
    int n   = bid & 7;                      \
    int m   = bid >> 3;      /* 0..255 in-image tile */ \
    int pix = m * 64 + lane;                \
    int j = pix & (W_ - 1);                 \
    int i = pix >> 7;

// Per-(pixel,tap) setup -> LDS (threads t < 192). 2x2 tile base clamped
// in-image; corner weights routed to relative slots (round-6 verified).
#define TAP_SETUP_192(OFFP, MASKP, KYO, KXO)                                  \
    {                                                                         \
        int t = threadIdx.x;                                                  \
        if (t < 192) {                                                        \
            int p = t / 3, k = t - 3 * p;                                     \
            int pixp = m * 64 + p;                                            \
            float dy = (OFFP##_DY);                                           \
            float dx = (OFFP##_DX);                                           \
            float mm = (MASKP);                                               \
            float fi = (float)(pixp >> 7), fj = (float)(pixp & (W_ - 1));     \
            float py = fi + (float)(KYO) + dy;                                \
            float px = fj + (float)(KXO) + dx;                                \
            float y0f = floorf(py), x0f = floorf(px);                         \
            float wy = py - y0f, wx = px - x0f;                               \
            int y0 = (int)y0f, x0 = (int)x0f;                                 \
            int y1 = y0 + 1, x1 = x0 + 1;                                     \
            bool vy0 = (y0 >= 0) && (y0 < H_);                                \
            bool vy1 = (y1 >= 0) && (y1 < H_);                                \
            bool vx0 = (x0 >= 0) && (x0 < W_);                                \
            bool vx1 = (x1 >= 0) && (x1 < W_);                                \
            float wy1 = 1.f - wy, wx1 = 1.f - wx;                             \
            float w00 = (vy0 && vx0) ? wy1 * wx1 * mm : 0.f;                  \
            float w01 = (vy0 && vx1) ? wy1 * wx  * mm : 0.f;                  \
            float w10 = (vy1 && vx0) ? wy  * wx1 * mm : 0.f;                  \
            float w11 = (vy1 && vx1) ? wy  * wx  * mm : 0.f;                  \
            int y0c = min(max(y0, 0), H_ - 1), y1c = min(max(y1, 0), H_ - 1); \
            int x0c = min(max(x0, 0), W_ - 1), x1c = min(max(x1, 0), W_ - 1); \
            int yb = min(max(y0, 0), H_ - 2),  xb = min(max(x0, 0), W_ - 2);  \
            int r0 = y0c - yb, r1 = y1c - yb;   /* in {0,1} */                \
            int cA = x0c - xb, cB = x1c - xb;   /* in {0,1} */                \
            floatx4 w;                                                        \
            w[0] = ((r0==0)&&(cA==0)?w00:0.f) + ((r0==0)&&(cB==0)?w01:0.f)    \
                 + ((r1==0)&&(cA==0)?w10:0.f) + ((r1==0)&&(cB==0)?w11:0.f);   \
            w[1] = ((r0==0)&&(cA==1)?w00:0.f) + ((r0==0)&&(cB==1)?w01:0.f)    \
                 + ((r1==0)&&(cA==1)?w10:0.f) + ((r1==0)&&(cB==1)?w11:0.f);   \
            w[2] = ((r0==1)&&(cA==0)?w00:0.f) + ((r0==1)&&(cB==0)?w01:0.f)    \
                 + ((r1==1)&&(cA==0)?w10:0.f) + ((r1==1)&&(cB==0)?w11:0.f);   \
            w[3] = ((r0==1)&&(cA==1)?w00:0.f) + ((r0==1)&&(cB==1)?w01:0.f)    \
                 + ((r1==1)&&(cA==1)?w10:0.f) + ((r1==1)&&(cB==1)?w11:0.f);   \
            tapI[t] = (yb * W_ + xb) * 64;                                    \
            tapW[t] = w;                                                      \
        }                                                                     \
    }

// NHWC gather + MFMA over two 32-pixel halves (round-6 verified). Wave-
// uniform base in SGPR via readfirstlane; conflict-free valT writes
// (K' = k*64 + lane -> contiguous 128-B wave store). All reads in-image.
#define GATHER_MFMA_BODY(ST)                                                  \
    int col = lane & 15;                                                      \
    floatx4 accT[4];                                                          \
    _Pragma("unroll")                                                         \
    for (int T = 0; T < 4; ++T) accT[T] = floatx4{0.f, 0.f, 0.f, 0.f};        \
    _Pragma("unroll")                                                         \
    for (int hf = 0; hf < 2; ++hf) {                                          \
        _Pragma("unroll")                                                     \
        for (int q = 0; q < 8; ++q) {                                         \
            int r = wv * 8 + q;                                               \
            int p = hf * 32 + r;                                              \
            _Pragma("unroll")                                                 \
            for (int k = 0; k < 3; ++k) {                                     \
                int ex = __builtin_amdgcn_readfirstlane(tapI[p * 3 + k]);     \
                floatx4 w = tapW[p * 3 + k];                                  \
                const _Float16* cb = (ST) + ex;                               \
                float v00 = (float)cb[lane];                                  \
                float v01 = (float)cb[lane + 64];                             \
                float v10 = (float)cb[lane + 64 * W_];                        \
                float v11 = (float)cb[lane + 64 * W_ + 64];                   \
                float v = fmaf(w[0], v00, fmaf(w[1], v01,                     \
                          fmaf(w[2], v10, w[3] * v11)));                      \
                valT[r][k * 64 + lane] = (_Float16)v;                         \
            }                                                                 \
        }                                                                     \
        __syncthreads();                                                      \
        const _Float16* wpA = wF16 + (size_t)(c0 + (lane & 15)) * 192         \
                            + ((lane >> 4) << 3);                             \
        half8 A0 = *((const half8*)(wpA +   0));                              \
        half8 A1 = *((const half8*)(wpA +  32));                              \
        half8 A2 = *((const half8*)(wpA +  64));                              \
        half8 A3 = *((const half8*)(wpA +  96));                              \
        half8 A4 = *((const half8*)(wpA + 128));                              \
        half8 A5 = *((const half8*)(wpA + 160));                              \
        _Pragma("unroll")                                                     \
        for (int tt = 0; tt < 2; ++tt) {                                      \
            int T = hf * 2 + tt;                                              \
            const _Float16* bp = &valT[tt * 16 + col][(lane >> 4) << 3];      \
            floatx4 acc = accT[T];                                            \
            acc = __builtin_amdgcn_mfma_f32_16x16x32_f16(A0, *((const half8*)(bp +   0)), acc, 0, 0, 0); \
            acc = __builtin_amdgcn_mfma_f32_16x16x32_f16(A1, *((const half8*)(bp +  32)), acc, 0, 0, 0); \
            acc = __builtin_amdgcn_mfma_f32_16x16x32_f16(A2, *((const half8*)(bp +  64)), acc, 0, 0, 0); \
            acc = __builtin_amdgcn_mfma_f32_16x16x32_f16(A3, *((const half8*)(bp +  96)), acc, 0, 0, 0); \
            acc = __builtin_amdgcn_mfma_f32_16x16x32_f16(A4, *((const half8*)(bp + 128)), acc, 0, 0, 0); \
            acc = __builtin_amdgcn_mfma_f32_16x16x32_f16(A5, *((const half8*)(bp + 160)), acc, 0, 0, 0); \
            accT[T] = acc;                                                    \
        }                                                                     \
        if (hf == 0) __syncthreads();                                         \
    }

// ---------------------------------------------------------------------------
// Fused horizontal pass — ROUND-6 FORM (round-7's MFMA prologue regressed:
// Bbuf wave-reuse serialized LDS store->MFMA-read across ck iterations).
// VALU prologue reads x NCHW (coalesced); gathers read xT NHWC.
// ---------------------------------------------------------------------------
__global__ __launch_bounds__(256, 8) void deform_h_kernel(
    const float* __restrict__ x, const _Float16* __restrict__ xT,
    const float* __restrict__ wOffAll,
    const float* __restrict__ b_off_h, const float* __restrict__ b_mask_h,
    const float* __restrict__ b_off_v, const float* __restrict__ b_mask_v,
    const _Float16* __restrict__ wF16, const float* __restrict__ bias,
    float* __restrict__ off_v, float* __restrict__ mask_v,
    _Float16* __restrict__ x_hT)
{
    __shared__ __align__(16) char smem[18432];
    float (*red)[18][64] = reinterpret_cast<float(*)[18][64]>(smem);
    float (*red0)[64]    = reinterpret_cast<float(*)[64]>(smem);
    _Float16 (*valT)[200] = reinterpret_cast<_Float16(*)[200]>(smem);  // 32 rows
    int*     tapI = reinterpret_cast<int*>(smem + 12800);     // 768 B
    floatx4* tapW = reinterpret_cast<floatx4*>(smem + 13568); // 3072 B

    int lane = threadIdx.x & 63;
    int wv   = threadIdx.x >> 6;
    int c0 = __builtin_amdgcn_readfirstlane(wv << 4);   // SGPR slice base

    SWIZZLE_NP();

    // ---- offs prologue: 5-pt stencil over this wave's 16 channels ----
    float a[18];
    #pragma unroll
    for (int o = 0; o < 18; ++o) a[o] = 0.f;

    const float* xs = x + (size_t)n * C_ * HW_ + (size_t)c0 * HW_;
    for (int cc = 0; cc < 16; ++cc) {
        const float* s = xs + cc * HW_;
        float xc = s[pix];
        float xl = (j > 0)      ? s[pix - 1]  : 0.f;
        float xr = (j < W_ - 1) ? s[pix + 1]  : 0.f;
        float xu = (i > 0)      ? s[pix - W_] : 0.f;
        float xd = (i < H_ - 1) ? s[pix + W_] : 0.f;
        const float* wc = wOffAll + (c0 + cc) * 56;   // uniform -> s_load
        #pragma unroll
        for (int o = 0; o < 6; ++o) {
            a[o]   = fmaf(xl, wc[3*o],    fmaf(xc, wc[3*o+1],    fmaf(xr, wc[3*o+2],    a[o])));
            a[9+o] = fmaf(xu, wc[27+3*o], fmaf(xc, wc[27+3*o+1], fmaf(xd, wc[27+3*o+2], a[9+o])));
        }
        #pragma unroll
        for (int o = 0; o < 3; ++o) {
            a[6+o]  = fmaf(xl, wc[18+3*o], fmaf(xc, wc[18+3*o+1], fmaf(xr, wc[18+3*o+2], a[6+o])));
            a[15+o] = fmaf(xu, wc[45+3*o], fmaf(xc, wc[45+3*o+1], fmaf(xd, wc[45+3*o+2], a[15+o])));
        }
    }

    // ---- cross-wave reduce: h-set -> red0, v-set -> ws ----
    #pragma unroll
    for (int o = 0; o < 18; ++o) red[wv][o][lane] = a[o];
    __syncthreads();

    for (int v = threadIdx.x; v < 18 * 64; v += 256) {
        int idx = v >> 6;
        int px  = v & 63;
        float sum = red[0][idx][px] + red[1][idx][px]
                  + red[2][idx][px] + red[3][idx][px];
        int pixg = m * 64 + px;
        if (idx < 6) {
            red[0][idx][px] = sum + b_off_h[idx];    // (idx,px) has unique owner
        } else if (idx < 9) {
            red[0][idx][px] = 1.f / (1.f + __expf(-(sum + b_mask_h[idx - 6])));
        } else if (idx < 15) {
            off_v[((size_t)n * 6 + (idx - 9)) * HW_ + pixg] = sum + b_off_v[idx - 9];
        } else {
            mask_v[((size_t)n * 3 + (idx - 15)) * HW_ + pixg] =
                1.f / (1.f + __expf(-(sum + b_mask_v[idx - 15])));
        }
    }
    __syncthreads();

    // ---- tap setup (horizontal: kyo=0, kxo=k-1) from red0 ----
#define H_DY red0[2*k    ][p]
#define H_DX red0[2*k + 1][p]
    TAP_SETUP_192(H, red0[6 + k][p], 0, (k - 1))
#undef H_DY
#undef H_DX
    __syncthreads();   // tap reads of red0 done before valT overwrites

    const _Float16* sT = xT + (size_t)n * (HW_ * 64);
    GATHER_MFMA_BODY(sT)

    // ---- epilogue: NHWC f16 store, one half4 per tile ----
    int orow = c0 + ((lane >> 4) << 2);
    floatx4 bv = *((const floatx4*)&bias[orow]);
    _Float16* hb = x_hT + ((size_t)n * HW_ + (size_t)m * 64) * 64 + orow;
    #pragma unroll
    for (int T = 0; T < 4; ++T) {
        half4 o;
        o[0] = (_Float16)(accT[T][0] + bv[0]);
        o[1] = (_Float16)(accT[T][1] + bv[1]);
        o[2] = (_Float16)(accT[T][2] + bv[2]);
        o[3] = (_Float16)(accT[T][3] + bv[3]);
        *((half4*)(hb + (size_t)(T * 16 + col) * 64)) = o;
    }
}

// ---------------------------------------------------------------------------
// Vertical pass (round-6 structure, unchanged).
// ---------------------------------------------------------------------------
__global__ __launch_bounds__(256, 8) void deform_v_kernel(
    const _Float16* __restrict__ srcT, const float* __restrict__ off,
    const float* __restrict__ mask, const _Float16* __restrict__ wF16,
    const float* __restrict__ bias, float* __restrict__ out)
{
    __shared__ __align__(16) char smem[16640];
    _Float16 (*valT)[200] = reinterpret_cast<_Float16(*)[200]>(smem);
    int*     tapI = reinterpret_cast<int*>(smem + 12800);     // 768 B
    floatx4* tapW = reinterpret_cast<floatx4*>(smem + 13568); // 3072 B

    int lane = threadIdx.x & 63;
    int wv   = threadIdx.x >> 6;
    int c0 = __builtin_amdgcn_readfirstlane(wv << 4);

    int bid = blockIdx.x;
    int n   = bid & 7;
    int m   = bid >> 3;

#define V_DY off[(((size_t)n * 3 + k) * 2 + 0) * HW_ + pixp]
#define V_DX off[(((size_t)n * 3 + k) * 2 + 1) * HW_ + pixp]
    TAP_SETUP_192(V, mask[((size_t)n * 3 + k) * HW_ + pixp], (k - 1), 0)
#undef V_DY
#undef V_DX
    __syncthreads();

    const _Float16* sT = srcT + (size_t)n * (HW_ * 64);
    GATHER_MFMA_BODY(sT)

    // ---- epilogue: out is NCHW f32 (reference layout), nt-stores ----
    int orow = c0 + ((lane >> 4) << 2);
    floatx4 bv = *((const floatx4*)&bias[orow]);
    float* ob = out + ((size_t)n * C_ + orow) * HW_ + m * 64 + col;
    #pragma unroll
    for (int T = 0; T < 4; ++T) {
        __builtin_nontemporal_store(accT[T][0] + bv[0], &ob[T * 16 + (size_t)0 * HW_]);
        __builtin_nontemporal_store(accT[T][1] + bv[1], &ob[T * 16 + (size_t)1 * HW_]);
        __builtin_nontemporal_store(accT[T][2] + bv[2], &ob[T * 16 + (size_t)2 * HW_]);
        __builtin_nontemporal_store(accT[T][3] + bv[3], &ob[T * 16 + (size_t)3 * HW_]);
    }
}

// ---------------------------------------------------------------------------
extern "C" void kernel_launch(void* const* d_in, const int* in_sizes, int n_in,
                              void* d_out, int out_size, void* d_ws, size_t ws_size,
                              hipStream_t stream)
{
    const float* x        = (const float*)d_in[0];
    const float* w_off_h  = (const float*)d_in[1];
    const float* b_off_h  = (const float*)d_in[2];
    const float* w_mask_h = (const float*)d_in[3];
    const float* b_mask_h = (const float*)d_in[4];
    const float* w_off_v  = (const float*)d_in[5];
    const float* b_off_v  = (const float*)d_in[6];
    const float* w_mask_v = (const float*)d_in[7];
    const float* b_mask_v = (const float*)d_in[8];
    const float* w_h      = (const float*)d_in[9];
    const float* b_h      = (const float*)d_in[10];
    const float* w_v      = (const float*)d_in[11];
    const float* b_v      = (const float*)d_in[12];

    // ws: f32 region then f16 region; ~38.3 MB (round-6 layout).
    float* ws      = (float*)d_ws;
    float* off_v   = ws;                    // 786432 f32
    float* mask_v  = off_v  + 786432;       // 393216 f32
    float* wOffAll = mask_v + 393216;       // 3584 f32
    _Float16* xT     = (_Float16*)(wOffAll + 3584);   // 8388608 f16 (x NHWC)
    _Float16* x_hT   = xT + 8388608;                  // 8388608 f16 (x_h NHWC)
    _Float16* wF16_h = x_hT + 8388608;                // 12288 f16
    _Float16* wF16_v = wF16_h + 12288;                // 12288 f16

    dim3 grid(NPIX / 64), block(256);

    setup_kernel<<<grid, block, 0, stream>>>(
        x, xT, w_off_h, w_mask_h, w_off_v, w_mask_v, w_h, w_v,
        wOffAll, wF16_h, wF16_v);

    deform_h_kernel<<<grid, block, 0, stream>>>(
        x, xT, wOffAll, b_off_h, b_mask_h, b_off_v, b_mask_v,
        wF16_h, b_h, off_v, mask_v, x_hT);

    deform_v_kernel<<<grid, block, 0, stream>>>(
        x_hT, off_v, mask_v, wF16_v, b_v, (float*)d_out);
}

// Round 9
// 188.528 us; speedup vs baseline: 1.0602x; 1.0093x over previous
//
#include <hip/hip_runtime.h>

#define C_ 64
#define H_ 128
#define W_ 128
#define B_ 8
#define HW_ (H_*W_)
#define NPIX (B_*HW_)

typedef _Float16 half8 __attribute__((ext_vector_type(8)));
typedef _Float16 half4 __attribute__((ext_vector_type(4)));
typedef float floatx4 __attribute__((ext_vector_type(4)));

// readlane helpers (compile-time lane index)
#define RDL_I(v, l) __builtin_amdgcn_readlane((v), (l))
#define RDL_F(v, l) __builtin_bit_cast(float, \
    __builtin_amdgcn_readlane(__builtin_bit_cast(int, (v)), (l)))

// ---------------------------------------------------------------------------
// Setup: weight prep (first blocks) + NCHW->NHWC f16 transpose (all blocks).
// ---------------------------------------------------------------------------
__global__ __launch_bounds__(256, 8) void setup_kernel(
    const float* __restrict__ x, _Float16* __restrict__ xT,
    const float* __restrict__ w_off_h, const float* __restrict__ w_mask_h,
    const float* __restrict__ w_off_v, const float* __restrict__ w_mask_v,
    const float* __restrict__ w_h, const float* __restrict__ w_v,
    float* __restrict__ wOffAll, _Float16* __restrict__ wF16_h,
    _Float16* __restrict__ wF16_v)
{
    int gid = blockIdx.x * 256 + threadIdx.x;
    if (gid < 64 * 56) {
        int c = gid / 56, idx = gid - 56 * c;
        float v = 0.f;
        if (idx < 18)      v = w_off_h [((idx      ) / 3) * 192 + c * 3 + (idx      ) % 3];
        else if (idx < 27) v = w_mask_h[((idx - 18) / 3) * 192 + c * 3 + (idx - 18) % 3];
        else if (idx < 45) v = w_off_v [((idx - 27) / 3) * 192 + c * 3 + (idx - 27) % 3];
        else if (idx < 54) v = w_mask_v[((idx - 45) / 3) * 192 + c * 3 + (idx - 45) % 3];
        wOffAll[c * 56 + idx] = v;
    } else if (gid < 3584 + 24576) {
        int i = gid - 3584;
        if (i < 12288) {
            int o = i / 192, rem = i - o * 192;
            int c = rem / 3, k = rem - 3 * c;
            wF16_h[o * 192 + k * 64 + c] = (_Float16)w_h[i];
        } else {
            i -= 12288;
            int o = i / 192, rem = i - o * 192;
            int c = rem / 3, k = rem - 3 * c;
            wF16_v[o * 192 + k * 64 + c] = (_Float16)w_v[i];
        }
    }

    __shared__ _Float16 tile[64][66];
    int lane = threadIdx.x & 63;
    int wv   = threadIdx.x >> 6;
    int bid = blockIdx.x;
    int n = bid & 7;          // XCD-pinned, same mapping as consumers
    int m = bid >> 3;
    const float* xs = x + (size_t)n * C_ * HW_ + (size_t)m * 64;
    #pragma unroll
    for (int cc = 0; cc < 16; ++cc) {
        int c = wv * 16 + cc;
        tile[c][lane] = (_Float16)xs[(size_t)c * HW_ + lane];
    }
    __syncthreads();
    _Float16* xd = xT + ((size_t)n * HW_ + (size_t)m * 64) * 64;
    #pragma unroll
    for (int pp = 0; pp < 16; ++pp) {
        int p = wv * 16 + pp;
        xd[(size_t)p * 64 + lane] = tile[lane][p];
    }
}

// XCD-aware swizzle: one image (n) pinned to XCD n (bid&7).
#define SWIZZLE_NP()                        \
    int bid = blockIdx.x;                   \
    int n   = bid & 7;                      \
    int m   = bid >> 3;      /* 0..255 in-image tile */ \
    int pix = m * 64 + lane;                \
    int j = pix & (W_ - 1);                 \
    int i = pix >> 7;

// ---------------------------------------------------------------------------
// Round-9: per-WAVE tap compute in lanes 0..47 — NO LDS for taps. Lane l
// handles (local_idx = l/3, k = l%3); local_idx 0..7 -> pixel wv*8+li (half 0),
// 8..15 -> 32+wv*8+(li-8) (half 1). Results stay in per-lane registers
// (tI, tw0..tw3); the gather reads them via v_readlane at compile-time lane
// (hf*8+q)*3+k. Same f32 arithmetic as round-6 (absmax canary).
// 2x2 tile base clamped in-image; corner weights routed to relative slots.
// DYE/DXE/MME are expressions in (p [block-local pixel], pixp [global], k).
// ---------------------------------------------------------------------------
#define TAP_WAVE48(DYE, DXE, MME, KYO, KXO)                                   \
    int   tI  = 0;                                                            \
    float tw0 = 0.f, tw1 = 0.f, tw2 = 0.f, tw3 = 0.f;                         \
    {                                                                         \
        int li = lane / 3, k = lane - 3 * li;                                 \
        if (lane < 48) {                                                      \
            int p = (li < 8) ? (wv * 8 + li) : (32 + wv * 8 + (li - 8));      \
            int pixp = m * 64 + p;                                            \
            float dy = (DYE);                                                 \
            float dx = (DXE);                                                 \
            float mm = (MME);                                                 \
            float fi = (float)(pixp >> 7), fj = (float)(pixp & (W_ - 1));     \
            float py = fi + (float)(KYO) + dy;                                \
            float px = fj + (float)(KXO) + dx;                                \
            float y0f = floorf(py), x0f = floorf(px);                         \
            float wy = py - y0f, wx = px - x0f;                               \
            int y0 = (int)y0f, x0 = (int)x0f;                                 \
            int y1 = y0 + 1, x1 = x0 + 1;                                     \
            bool vy0 = (y0 >= 0) && (y0 < H_);                                \
            bool vy1 = (y1 >= 0) && (y1 < H_);                                \
            bool vx0 = (x0 >= 0) && (x0 < W_);                                \
            bool vx1 = (x1 >= 0) && (x1 < W_);                                \
            float wy1 = 1.f - wy, wx1 = 1.f - wx;                             \
            float w00 = (vy0 && vx0) ? wy1 * wx1 * mm : 0.f;                  \
            float w01 = (vy0 && vx1) ? wy1 * wx  * mm : 0.f;                  \
            float w10 = (vy1 && vx0) ? wy  * wx1 * mm : 0.f;                  \
            float w11 = (vy1 && vx1) ? wy  * wx  * mm : 0.f;                  \
            int y0c = min(max(y0, 0), H_ - 1), y1c = min(max(y1, 0), H_ - 1); \
            int x0c = min(max(x0, 0), W_ - 1), x1c = min(max(x1, 0), W_ - 1); \
            int yb = min(max(y0, 0), H_ - 2),  xb = min(max(x0, 0), W_ - 2);  \
            int r0 = y0c - yb, r1 = y1c - yb;   /* in {0,1} */                \
            int cA = x0c - xb, cB = x1c - xb;   /* in {0,1} */                \
            tw0 = ((r0==0)&&(cA==0)?w00:0.f) + ((r0==0)&&(cB==0)?w01:0.f)     \
                + ((r1==0)&&(cA==0)?w10:0.f) + ((r1==0)&&(cB==0)?w11:0.f);    \
            tw1 = ((r0==0)&&(cA==1)?w00:0.f) + ((r0==0)&&(cB==1)?w01:0.f)     \
                + ((r1==0)&&(cA==1)?w10:0.f) + ((r1==0)&&(cB==1)?w11:0.f);    \
            tw2 = ((r0==1)&&(cA==0)?w00:0.f) + ((r0==1)&&(cB==0)?w01:0.f)     \
                + ((r1==1)&&(cA==0)?w10:0.f) + ((r1==1)&&(cB==0)?w11:0.f);    \
            tw3 = ((r0==1)&&(cA==1)?w00:0.f) + ((r0==1)&&(cB==1)?w01:0.f)     \
                + ((r1==1)&&(cA==1)?w10:0.f) + ((r1==1)&&(cB==1)?w11:0.f);    \
            tI = (yb * W_ + xb) * 64;                                         \
        }                                                                     \
    }

// NHWC gather + MFMA over two 32-pixel halves. Taps from registers via
// readlane (SGPR base + SGPR weights) — zero LDS on the address path.
// Conflict-free valT writes (K' = k*64 + lane -> contiguous 128-B store).
#define GATHER_MFMA_BODY(ST)                                                  \
    int col = lane & 15;                                                      \
    floatx4 accT[4];                                                          \
    _Pragma("unroll")                                                         \
    for (int T = 0; T < 4; ++T) accT[T] = floatx4{0.f, 0.f, 0.f, 0.f};        \
    _Pragma("unroll")                                                         \
    for (int hf = 0; hf < 2; ++hf) {                                          \
        _Pragma("unroll")                                                     \
        for (int q = 0; q < 8; ++q) {                                         \
            int r = wv * 8 + q;                                               \
            _Pragma("unroll")                                                 \
            for (int k = 0; k < 3; ++k) {                                     \
                const int tl = (hf * 8 + q) * 3 + k;                          \
                int ex   = RDL_I(tI, tl);                                     \
                float w0 = RDL_F(tw0, tl);                                    \
                float w1 = RDL_F(tw1, tl);                                    \
                float w2 = RDL_F(tw2, tl);                                    \
                float w3 = RDL_F(tw3, tl);                                    \
                const _Float16* cb = (ST) + ex;                               \
                float v00 = (float)cb[lane];                                  \
                float v01 = (float)cb[lane + 64];                             \
                float v10 = (float)cb[lane + 64 * W_];                        \
                float v11 = (float)cb[lane + 64 * W_ + 64];                   \
                float v = fmaf(w0, v00, fmaf(w1, v01,                         \
                          fmaf(w2, v10, w3 * v11)));                          \
                valT[r][k * 64 + lane] = (_Float16)v;                         \
            }                                                                 \
        }                                                                     \
        __syncthreads();                                                      \
        const _Float16* wpA = wF16 + (size_t)(c0 + (lane & 15)) * 192         \
                            + ((lane >> 4) << 3);                             \
        half8 A0 = *((const half8*)(wpA +   0));                              \
        half8 A1 = *((const half8*)(wpA +  32));                              \
        half8 A2 = *((const half8*)(wpA +  64));                              \
        half8 A3 = *((const half8*)(wpA +  96));                              \
        half8 A4 = *((const half8*)(wpA + 128));                              \
        half8 A5 = *((const half8*)(wpA + 160));                              \
        _Pragma("unroll")                                                     \
        for (int tt = 0; tt < 2; ++tt) {                                      \
            int T = hf * 2 + tt;                                              \
            const _Float16* bp = &valT[tt * 16 + col][(lane >> 4) << 3];      \
            floatx4 acc = accT[T];                                            \
            acc = __builtin_amdgcn_mfma_f32_16x16x32_f16(A0, *((const half8*)(bp +   0)), acc, 0, 0, 0); \
            acc = __builtin_amdgcn_mfma_f32_16x16x32_f16(A1, *((const half8*)(bp +  32)), acc, 0, 0, 0); \
            acc = __builtin_amdgcn_mfma_f32_16x16x32_f16(A2, *((const half8*)(bp +  64)), acc, 0, 0, 0); \
            acc = __builtin_amdgcn_mfma_f32_16x16x32_f16(A3, *((const half8*)(bp +  96)), acc, 0, 0, 0); \
            acc = __builtin_amdgcn_mfma_f32_16x16x32_f16(A4, *((const half8*)(bp + 128)), acc, 0, 0, 0); \
            acc = __builtin_amdgcn_mfma_f32_16x16x32_f16(A5, *((const half8*)(bp + 160)), acc, 0, 0, 0); \
            accT[T] = acc;                                                    \
        }                                                                     \
        if (hf == 0) __syncthreads();                                         \
    }

// ---------------------------------------------------------------------------
// Fused horizontal pass. VALU prologue (r6-verified) -> in-place red0 scatter
// -> per-wave register taps -> gather+MFMA. One barrier between tap reads of
// red0 and valT overwriting the same smem.
// ---------------------------------------------------------------------------
__global__ __launch_bounds__(256, 8) void deform_h_kernel(
    const float* __restrict__ x, const _Float16* __restrict__ xT,
    const float* __restrict__ wOffAll,
    const float* __restrict__ b_off_h, const float* __restrict__ b_mask_h,
    const float* __restrict__ b_off_v, const float* __restrict__ b_mask_v,
    const _Float16* __restrict__ wF16, const float* __restrict__ bias,
    float* __restrict__ off_v, float* __restrict__ mask_v,
    _Float16* __restrict__ x_hT)
{
    __shared__ __align__(16) char smem[18432];
    float (*red)[18][64] = reinterpret_cast<float(*)[18][64]>(smem);
    float (*red0)[64]    = reinterpret_cast<float(*)[64]>(smem);
    _Float16 (*valT)[200] = reinterpret_cast<_Float16(*)[200]>(smem);  // 32 rows

    int lane = threadIdx.x & 63;
    int wv   = threadIdx.x >> 6;
    int c0 = __builtin_amdgcn_readfirstlane(wv << 4);   // SGPR slice base

    SWIZZLE_NP();

    // ---- offs prologue: 5-pt stencil over this wave's 16 channels ----
    float a[18];
    #pragma unroll
    for (int o = 0; o < 18; ++o) a[o] = 0.f;

    const float* xs = x + (size_t)n * C_ * HW_ + (size_t)c0 * HW_;
    for (int cc = 0; cc < 16; ++cc) {
        const float* s = xs + cc * HW_;
        float xc = s[pix];
        float xl = (j > 0)      ? s[pix - 1]  : 0.f;
        float xr = (j < W_ - 1) ? s[pix + 1]  : 0.f;
        float xu = (i > 0)      ? s[pix - W_] : 0.f;
        float xd = (i < H_ - 1) ? s[pix + W_] : 0.f;
        const float* wc = wOffAll + (c0 + cc) * 56;   // uniform -> s_load
        #pragma unroll
        for (int o = 0; o < 6; ++o) {
            a[o]   = fmaf(xl, wc[3*o],    fmaf(xc, wc[3*o+1],    fmaf(xr, wc[3*o+2],    a[o])));
            a[9+o] = fmaf(xu, wc[27+3*o], fmaf(xc, wc[27+3*o+1], fmaf(xd, wc[27+3*o+2], a[9+o])));
        }
        #pragma unroll
        for (int o = 0; o < 3; ++o) {
            a[6+o]  = fmaf(xl, wc[18+3*o], fmaf(xc, wc[18+3*o+1], fmaf(xr, wc[18+3*o+2], a[6+o])));
            a[15+o] = fmaf(xu, wc[45+3*o], fmaf(xc, wc[45+3*o+1], fmaf(xd, wc[45+3*o+2], a[15+o])));
        }
    }

    // ---- cross-wave reduce: h-set -> red0 (in-place), v-set -> ws ----
    #pragma unroll
    for (int o = 0; o < 18; ++o) red[wv][o][lane] = a[o];
    __syncthreads();

    for (int v = threadIdx.x; v < 18 * 64; v += 256) {
        int idx = v >> 6;
        int px  = v & 63;
        float sum = red[0][idx][px] + red[1][idx][px]
                  + red[2][idx][px] + red[3][idx][px];
        int pixg = m * 64 + px;
        if (idx < 6) {
            red[0][idx][px] = sum + b_off_h[idx];    // (idx,px) has unique owner
        } else if (idx < 9) {
            red[0][idx][px] = 1.f / (1.f + __expf(-(sum + b_mask_h[idx - 6])));
        } else if (idx < 15) {
            off_v[((size_t)n * 6 + (idx - 9)) * HW_ + pixg] = sum + b_off_v[idx - 9];
        } else {
            mask_v[((size_t)n * 3 + (idx - 15)) * HW_ + pixg] =
                1.f / (1.f + __expf(-(sum + b_mask_v[idx - 15])));
        }
    }
    __syncthreads();

    // ---- taps (horizontal: kyo=0, kxo=k-1) from red0 -> registers ----
    TAP_WAVE48(red0[2*k][p], red0[2*k + 1][p], red0[6 + k][p], 0, (k - 1))
    __syncthreads();   // all tap reads of red0 done before valT overwrites

    const _Float16* sT = xT + (size_t)n * (HW_ * 64);
    GATHER_MFMA_BODY(sT)

    // ---- epilogue: NHWC f16 store, one half4 per tile ----
    int orow = c0 + ((lane >> 4) << 2);
    floatx4 bv = *((const floatx4*)&bias[orow]);
    _Float16* hb = x_hT + ((size_t)n * HW_ + (size_t)m * 64) * 64 + orow;
    #pragma unroll
    for (int T = 0; T < 4; ++T) {
        half4 o;
        o[0] = (_Float16)(accT[T][0] + bv[0]);
        o[1] = (_Float16)(accT[T][1] + bv[1]);
        o[2] = (_Float16)(accT[T][2] + bv[2]);
        o[3] = (_Float16)(accT[T][3] + bv[3]);
        *((half4*)(hb + (size_t)(T * 16 + col) * 64)) = o;
    }
}

// ---------------------------------------------------------------------------
// Vertical pass: taps from global off/mask -> registers (no pre-gather
// barrier at all); coalesced NHWC gathers from x_hT. LDS = valT only.
// ---------------------------------------------------------------------------
__global__ __launch_bounds__(256, 8) void deform_v_kernel(
    const _Float16* __restrict__ srcT, const float* __restrict__ off,
    const float* __restrict__ mask, const _Float16* __restrict__ wF16,
    const float* __restrict__ bias, float* __restrict__ out)
{
    __shared__ __align__(16) _Float16 valT[32][200];   // 12800 B

    int lane = threadIdx.x & 63;
    int wv   = threadIdx.x >> 6;
    int c0 = __builtin_amdgcn_readfirstlane(wv << 4);

    int bid = blockIdx.x;
    int n   = bid & 7;
    int m   = bid >> 3;

    // ---- taps (vertical: kyo=k-1, kxo=0) from ws -> registers ----
    TAP_WAVE48(off[(((size_t)n * 3 + k) * 2 + 0) * HW_ + pixp],
               off[(((size_t)n * 3 + k) * 2 + 1) * HW_ + pixp],
               mask[((size_t)n * 3 + k) * HW_ + pixp], (k - 1), 0)

    const _Float16* sT = srcT + (size_t)n * (HW_ * 64);
    GATHER_MFMA_BODY(sT)

    // ---- epilogue: out is NCHW f32 (reference layout), nt-stores ----
    int orow = c0 + ((lane >> 4) << 2);
    floatx4 bv = *((const floatx4*)&bias[orow]);
    float* ob = out + ((size_t)n * C_ + orow) * HW_ + m * 64 + col;
    #pragma unroll
    for (int T = 0; T < 4; ++T) {
        __builtin_nontemporal_store(accT[T][0] + bv[0], &ob[T * 16 + (size_t)0 * HW_]);
        __builtin_nontemporal_store(accT[T][1] + bv[1], &ob[T * 16 + (size_t)1 * HW_]);
        __builtin_nontemporal_store(accT[T][2] + bv[2], &ob[T * 16 + (size_t)2 * HW_]);
        __builtin_nontemporal_store(accT[T][3] + bv[3], &ob[T * 16 + (size_t)3 * HW_]);
    }
}

// ---------------------------------------------------------------------------
extern "C" void kernel_launch(void* const* d_in, const int* in_sizes, int n_in,
                              void* d_out, int out_size, void* d_ws, size_t ws_size,
                              hipStream_t stream)
{
    const float* x        = (const float*)d_in[0];
    const float* w_off_h  = (const float*)d_in[1];
    const float* b_off_h  = (const float*)d_in[2];
    const float* w_mask_h = (const float*)d_in[3];
    const float* b_mask_h = (const float*)d_in[4];
    const float* w_off_v  = (const float*)d_in[5];
    const float* b_off_v  = (const float*)d_in[6];
    const float* w_mask_v = (const float*)d_in[7];
    const float* b_mask_v = (const float*)d_in[8];
    const float* w_h      = (const float*)d_in[9];
    const float* b_h      = (const float*)d_in[10];
    const float* w_v      = (const float*)d_in[11];
    const float* b_v      = (const float*)d_in[12];

    // ws: f32 region then f16 region; ~38.3 MB (round-6 layout).
    float* ws      = (float*)d_ws;
    float* off_v   = ws;                    // 786432 f32
    float* mask_v  = off_v  + 786432;       // 393216 f32
    float* wOffAll = mask_v + 393216;       // 3584 f32
    _Float16* xT     = (_Float16*)(wOffAll + 3584);   // 8388608 f16 (x NHWC)
    _Float16* x_hT   = xT + 8388608;                  // 8388608 f16 (x_h NHWC)
    _Float16* wF16_h = x_hT + 8388608;                // 12288 f16
    _Float16* wF16_v = wF16_h + 12288;                // 12288 f16

    dim3 grid(NPIX / 64), block(256);

    setup_kernel<<<grid, block, 0, stream>>>(
        x, xT, w_off_h, w_mask_h, w_off_v, w_mask_v, w_h, w_v,
        wOffAll, wF16_h, wF16_v);

    deform_h_kernel<<<grid, block, 0, stream>>>(
        x, xT, wOffAll, b_off_h, b_mask_h, b_off_v, b_mask_v,
        wF16_h, b_h, off_v, mask_v, x_hT);

    deform_v_kernel<<<grid, block, 0, stream>>>(
        x_hT, off_v, mask_v, wF16_v, b_v, (float*)d_out);
}

// Round 10
// 187.721 us; speedup vs baseline: 1.0647x; 1.0043x over previous
//
#include <hip/hip_runtime.h>

#define C_ 64
#define H_ 128
#define W_ 128
#define B_ 8
#define HW_ (H_*W_)
#define NPIX (B_*HW_)

typedef _Float16 half8 __attribute__((ext_vector_type(8)));
typedef _Float16 half4 __attribute__((ext_vector_type(4)));
typedef float floatx4 __attribute__((ext_vector_type(4)));

// readlane helpers (compile-time lane index)
#define RDL_I(v, l) __builtin_amdgcn_readlane((v), (l))
#define RDL_F(v, l) __builtin_bit_cast(float, \
    __builtin_amdgcn_readlane(__builtin_bit_cast(int, (v)), (l)))

// ---------------------------------------------------------------------------
// Prep: wOffAll[c][56] packed f32 offset/mask weights + deform weights f16
// in K' = k*64 + c layout (matches conflict-free valT writes). 110 blocks.
// ---------------------------------------------------------------------------
__global__ __launch_bounds__(256) void prep_kernel(
    const float* __restrict__ w_off_h, const float* __restrict__ w_mask_h,
    const float* __restrict__ w_off_v, const float* __restrict__ w_mask_v,
    const float* __restrict__ w_h, const float* __restrict__ w_v,
    float* __restrict__ wOffAll, _Float16* __restrict__ wF16_h,
    _Float16* __restrict__ wF16_v)
{
    int gid = blockIdx.x * 256 + threadIdx.x;
    if (gid < 64 * 56) {
        int c = gid / 56, idx = gid - 56 * c;
        float v = 0.f;
        if (idx < 18)      v = w_off_h [((idx      ) / 3) * 192 + c * 3 + (idx      ) % 3];
        else if (idx < 27) v = w_mask_h[((idx - 18) / 3) * 192 + c * 3 + (idx - 18) % 3];
        else if (idx < 45) v = w_off_v [((idx - 27) / 3) * 192 + c * 3 + (idx - 27) % 3];
        else if (idx < 54) v = w_mask_v[((idx - 45) / 3) * 192 + c * 3 + (idx - 45) % 3];
        wOffAll[c * 56 + idx] = v;
    } else if (gid < 3584 + 24576) {
        int i = gid - 3584;
        if (i < 12288) {
            int o = i / 192, rem = i - o * 192;
            int c = rem / 3, k = rem - 3 * c;
            wF16_h[o * 192 + k * 64 + c] = (_Float16)w_h[i];
        } else {
            i -= 12288;
            int o = i / 192, rem = i - o * 192;
            int c = rem / 3, k = rem - 3 * c;
            wF16_v[o * 192 + k * 64 + c] = (_Float16)w_v[i];
        }
    }
}

// XCD-aware swizzle: one image (n) pinned to XCD n (bid&7).
#define SWIZZLE_NP()                        \
    int bid = blockIdx.x;                   \
    int n   = bid & 7;                      \
    int m   = bid >> 3;      /* 0..255 in-image tile */ \
    int pix = m * 64 + lane;                \
    int j = pix & (W_ - 1);                 \
    int i = pix >> 7;

// Shared transpose phase: NCHW f32 -> NHWC f16 through padded LDS tile.
#define TRANSPOSE_PHASE(TILE)                                                 \
    {                                                                         \
        const float* xs_t = x + (size_t)n * C_ * HW_ + (size_t)m * 64;        \
        _Pragma("unroll")                                                     \
        for (int cc = 0; cc < 16; ++cc) {                                     \
            int c = wv * 16 + cc;                                             \
            (TILE)[c][lane] = (_Float16)xs_t[(size_t)c * HW_ + lane];         \
        }                                                                     \
        __syncthreads();                                                      \
        _Float16* xd = xT + ((size_t)n * HW_ + (size_t)m * 64) * 64;          \
        _Pragma("unroll")                                                     \
        for (int pp = 0; pp < 16; ++pp) {                                     \
            int p = wv * 16 + pp;                                             \
            xd[(size_t)p * 64 + lane] = (TILE)[lane][p];                      \
        }                                                                     \
    }

// r6-verified VALU prologue: 5-pt stencil, 18 accumulators, per-wave 16 chans.
#define PROLOGUE_STENCIL()                                                    \
    float a[18];                                                              \
    _Pragma("unroll")                                                         \
    for (int o = 0; o < 18; ++o) a[o] = 0.f;                                  \
    {                                                                         \
        const float* xs = x + (size_t)n * C_ * HW_ + (size_t)c0 * HW_;        \
        for (int cc = 0; cc < 16; ++cc) {                                     \
            const float* s = xs + cc * HW_;                                   \
            float xc = s[pix];                                                \
            float xl = (j > 0)      ? s[pix - 1]  : 0.f;                      \
            float xr = (j < W_ - 1) ? s[pix + 1]  : 0.f;                      \
            float xu = (i > 0)      ? s[pix - W_] : 0.f;                      \
            float xd2 = (i < H_ - 1) ? s[pix + W_] : 0.f;                     \
            const float* wc = wOffAll + (c0 + cc) * 56;                       \
            _Pragma("unroll")                                                 \
            for (int o = 0; o < 6; ++o) {                                     \
                a[o]   = fmaf(xl, wc[3*o],    fmaf(xc, wc[3*o+1],    fmaf(xr, wc[3*o+2],    a[o])));    \
                a[9+o] = fmaf(xu, wc[27+3*o], fmaf(xc, wc[27+3*o+1], fmaf(xd2, wc[27+3*o+2], a[9+o]))); \
            }                                                                 \
            _Pragma("unroll")                                                 \
            for (int o = 0; o < 3; ++o) {                                     \
                a[6+o]  = fmaf(xl, wc[18+3*o], fmaf(xc, wc[18+3*o+1], fmaf(xr, wc[18+3*o+2], a[6+o])));    \
                a[15+o] = fmaf(xu, wc[45+3*o], fmaf(xc, wc[45+3*o+1], fmaf(xd2, wc[45+3*o+2], a[15+o]))); \
            }                                                                 \
        }                                                                     \
    }

// ---------------------------------------------------------------------------
// Round-10 (big-ws path): setup = transpose + FULL 18-output prologue.
// All offset/mask planes go to ws; deform_h no longer touches x f32, so its
// XCD working set (xT + off_h + x_hT ~ 5.4 MB) mostly L2-hits.
// smem: phase A tile[64][66] f16 (8448 B) -> phase B red[4][18][64] (18432 B).
// ---------------------------------------------------------------------------
__global__ __launch_bounds__(256, 8) void setup_big_kernel(
    const float* __restrict__ x, _Float16* __restrict__ xT,
    const float* __restrict__ wOffAll,
    const float* __restrict__ b_off_h, const float* __restrict__ b_mask_h,
    const float* __restrict__ b_off_v, const float* __restrict__ b_mask_v,
    float* __restrict__ off_h, float* __restrict__ mask_h,
    float* __restrict__ off_v, float* __restrict__ mask_v)
{
    __shared__ __align__(16) char smem[18432];
    _Float16 (*tile)[66] = reinterpret_cast<_Float16(*)[66]>(smem);
    float (*red)[18][64] = reinterpret_cast<float(*)[18][64]>(smem);

    int lane = threadIdx.x & 63;
    int wv   = threadIdx.x >> 6;
    int c0 = __builtin_amdgcn_readfirstlane(wv << 4);

    SWIZZLE_NP();

    TRANSPOSE_PHASE(tile)
    __syncthreads();            // tile dead before red overwrites

    PROLOGUE_STENCIL()

    #pragma unroll
    for (int o = 0; o < 18; ++o) red[wv][o][lane] = a[o];
    __syncthreads();

    for (int v = threadIdx.x; v < 18 * 64; v += 256) {
        int idx = v >> 6;
        int px  = v & 63;
        float sum = red[0][idx][px] + red[1][idx][px]
                  + red[2][idx][px] + red[3][idx][px];
        int pixg = m * 64 + px;
        if (idx < 6) {
            off_h[((size_t)n * 6 + idx) * HW_ + pixg] = sum + b_off_h[idx];
        } else if (idx < 9) {
            mask_h[((size_t)n * 3 + (idx - 6)) * HW_ + pixg] =
                1.f / (1.f + __expf(-(sum + b_mask_h[idx - 6])));
        } else if (idx < 15) {
            off_v[((size_t)n * 6 + (idx - 9)) * HW_ + pixg] = sum + b_off_v[idx - 9];
        } else {
            mask_v[((size_t)n * 3 + (idx - 15)) * HW_ + pixg] =
                1.f / (1.f + __expf(-(sum + b_mask_v[idx - 15])));
        }
    }
}

// Fallback path: transpose only (ws too small for the off_h handoff).
__global__ __launch_bounds__(256, 8) void transpose_kernel(
    const float* __restrict__ x, _Float16* __restrict__ xT)
{
    __shared__ _Float16 tile[64][66];
    int lane = threadIdx.x & 63;
    int wv   = threadIdx.x >> 6;
    int bid = blockIdx.x;
    int n = bid & 7;
    int m = bid >> 3;
    TRANSPOSE_PHASE(tile)
}

// ---------------------------------------------------------------------------
// Per-wave tap compute in lanes 0..47 (r9-verified): results in registers,
// read back in the gather via v_readlane at compile-time lane indices.
// 2x2 tile base clamped in-image; corner weights routed to relative slots.
// ---------------------------------------------------------------------------
#define TAP_WAVE48(DYE, DXE, MME, KYO, KXO)                                   \
    int   tI  = 0;                                                            \
    float tw0 = 0.f, tw1 = 0.f, tw2 = 0.f, tw3 = 0.f;                         \
    {                                                                         \
        int li = lane / 3, k = lane - 3 * li;                                 \
        if (lane < 48) {                                                      \
            int p = (li < 8) ? (wv * 8 + li) : (32 + wv * 8 + (li - 8));      \
            int pixp = m * 64 + p;                                            \
            float dy = (DYE);                                                 \
            float dx = (DXE);                                                 \
            float mm = (MME);                                                 \
            float fi = (float)(pixp >> 7), fj = (float)(pixp & (W_ - 1));     \
            float py = fi + (float)(KYO) + dy;                                \
            float px = fj + (float)(KXO) + dx;                                \
            float y0f = floorf(py), x0f = floorf(px);                         \
            float wy = py - y0f, wx = px - x0f;                               \
            int y0 = (int)y0f, x0 = (int)x0f;                                 \
            int y1 = y0 + 1, x1 = x0 + 1;                                     \
            bool vy0 = (y0 >= 0) && (y0 < H_);                                \
            bool vy1 = (y1 >= 0) && (y1 < H_);                                \
            bool vx0 = (x0 >= 0) && (x0 < W_);                                \
            bool vx1 = (x1 >= 0) && (x1 < W_);                                \
            float wy1 = 1.f - wy, wx1 = 1.f - wx;                             \
            float w00 = (vy0 && vx0) ? wy1 * wx1 * mm : 0.f;                  \
            float w01 = (vy0 && vx1) ? wy1 * wx  * mm : 0.f;                  \
            float w10 = (vy1 && vx0) ? wy  * wx1 * mm : 0.f;                  \
            float w11 = (vy1 && vx1) ? wy  * wx  * mm : 0.f;                  \
            int y0c = min(max(y0, 0), H_ - 1), y1c = min(max(y1, 0), H_ - 1); \
            int x0c = min(max(x0, 0), W_ - 1), x1c = min(max(x1, 0), W_ - 1); \
            int yb = min(max(y0, 0), H_ - 2),  xb = min(max(x0, 0), W_ - 2);  \
            int r0 = y0c - yb, r1 = y1c - yb;   /* in {0,1} */                \
            int cA = x0c - xb, cB = x1c - xb;   /* in {0,1} */                \
            tw0 = ((r0==0)&&(cA==0)?w00:0.f) + ((r0==0)&&(cB==0)?w01:0.f)     \
                + ((r1==0)&&(cA==0)?w10:0.f) + ((r1==0)&&(cB==0)?w11:0.f);    \
            tw1 = ((r0==0)&&(cA==1)?w00:0.f) + ((r0==0)&&(cB==1)?w01:0.f)     \
                + ((r1==0)&&(cA==1)?w10:0.f) + ((r1==0)&&(cB==1)?w11:0.f);    \
            tw2 = ((r0==1)&&(cA==0)?w00:0.f) + ((r0==1)&&(cB==0)?w01:0.f)     \
                + ((r1==1)&&(cA==0)?w10:0.f) + ((r1==1)&&(cB==0)?w11:0.f);    \
            tw3 = ((r0==1)&&(cA==1)?w00:0.f) + ((r0==1)&&(cB==1)?w01:0.f)     \
                + ((r1==1)&&(cA==1)?w10:0.f) + ((r1==1)&&(cB==1)?w11:0.f);    \
            tI = (yb * W_ + xb) * 64;                                         \
        }                                                                     \
    }

// NHWC gather + MFMA over two 32-pixel halves (r9-verified).
#define GATHER_MFMA_BODY(ST)                                                  \
    int col = lane & 15;                                                      \
    floatx4 accT[4];                                                          \
    _Pragma("unroll")                                                         \
    for (int T = 0; T < 4; ++T) accT[T] = floatx4{0.f, 0.f, 0.f, 0.f};        \
    _Pragma("unroll")                                                         \
    for (int hf = 0; hf < 2; ++hf) {                                          \
        _Pragma("unroll")                                                     \
        for (int q = 0; q < 8; ++q) {                                         \
            int r = wv * 8 + q;                                               \
            _Pragma("unroll")                                                 \
            for (int k = 0; k < 3; ++k) {                                     \
                const int tl = (hf * 8 + q) * 3 + k;                          \
                int ex   = RDL_I(tI, tl);                                     \
                float w0 = RDL_F(tw0, tl);                                    \
                float w1 = RDL_F(tw1, tl);                                    \
                float w2 = RDL_F(tw2, tl);                                    \
                float w3 = RDL_F(tw3, tl);                                    \
                const _Float16* cb = (ST) + ex;                               \
                float v00 = (float)cb[lane];                                  \
                float v01 = (float)cb[lane + 64];                             \
                float v10 = (float)cb[lane + 64 * W_];                        \
                float v11 = (float)cb[lane + 64 * W_ + 64];                   \
                float v = fmaf(w0, v00, fmaf(w1, v01,                         \
                          fmaf(w2, v10, w3 * v11)));                          \
                valT[r][k * 64 + lane] = (_Float16)v;                         \
            }                                                                 \
        }                                                                     \
        __syncthreads();                                                      \
        const _Float16* wpA = wF16 + (size_t)(c0 + (lane & 15)) * 192         \
                            + ((lane >> 4) << 3);                             \
        half8 A0 = *((const half8*)(wpA +   0));                              \
        half8 A1 = *((const half8*)(wpA +  32));                              \
        half8 A2 = *((const half8*)(wpA +  64));                              \
        half8 A3 = *((const half8*)(wpA +  96));                              \
        half8 A4 = *((const half8*)(wpA + 128));                              \
        half8 A5 = *((const half8*)(wpA + 160));                              \
        _Pragma("unroll")                                                     \
        for (int tt = 0; tt < 2; ++tt) {                                      \
            int T = hf * 2 + tt;                                              \
            const _Float16* bp = &valT[tt * 16 + col][(lane >> 4) << 3];      \
            floatx4 acc = accT[T];                                            \
            acc = __builtin_amdgcn_mfma_f32_16x16x32_f16(A0, *((const half8*)(bp +   0)), acc, 0, 0, 0); \
            acc = __builtin_amdgcn_mfma_f32_16x16x32_f16(A1, *((const half8*)(bp +  32)), acc, 0, 0, 0); \
            acc = __builtin_amdgcn_mfma_f32_16x16x32_f16(A2, *((const half8*)(bp +  64)), acc, 0, 0, 0); \
            acc = __builtin_amdgcn_mfma_f32_16x16x32_f16(A3, *((const half8*)(bp +  96)), acc, 0, 0, 0); \
            acc = __builtin_amdgcn_mfma_f32_16x16x32_f16(A4, *((const half8*)(bp + 128)), acc, 0, 0, 0); \
            acc = __builtin_amdgcn_mfma_f32_16x16x32_f16(A5, *((const half8*)(bp + 160)), acc, 0, 0, 0); \
            accT[T] = acc;                                                    \
        }                                                                     \
        if (hf == 0) __syncthreads();                                         \
    }

// ---------------------------------------------------------------------------
// Slim horizontal pass (big-ws path): structurally identical to deform_v —
// taps from precomputed off_h/mask_h, NHWC gathers from xT, NHWC f16 output.
// ---------------------------------------------------------------------------
__global__ __launch_bounds__(256, 8) void deform_h_slim_kernel(
    const _Float16* __restrict__ srcT, const float* __restrict__ off,
    const float* __restrict__ mask, const _Float16* __restrict__ wF16,
    const float* __restrict__ bias, _Float16* __restrict__ x_hT)
{
    __shared__ __align__(16) _Float16 valT[32][200];   // 12800 B

    int lane = threadIdx.x & 63;
    int wv   = threadIdx.x >> 6;
    int c0 = __builtin_amdgcn_readfirstlane(wv << 4);

    int bid = blockIdx.x;
    int n   = bid & 7;
    int m   = bid >> 3;

    // taps (horizontal: kyo=0, kxo=k-1) from ws planes
    TAP_WAVE48(off[(((size_t)n * 3 + k) * 2 + 0) * HW_ + pixp],
               off[(((size_t)n * 3 + k) * 2 + 1) * HW_ + pixp],
               mask[((size_t)n * 3 + k) * HW_ + pixp], 0, (k - 1))

    const _Float16* sT = srcT + (size_t)n * (HW_ * 64);
    GATHER_MFMA_BODY(sT)

    // epilogue: NHWC f16 (re-read by v -> plain stores)
    int orow = c0 + ((lane >> 4) << 2);
    floatx4 bv = *((const floatx4*)&bias[orow]);
    _Float16* hb = x_hT + ((size_t)n * HW_ + (size_t)m * 64) * 64 + orow;
    #pragma unroll
    for (int T = 0; T < 4; ++T) {
        half4 o;
        o[0] = (_Float16)(accT[T][0] + bv[0]);
        o[1] = (_Float16)(accT[T][1] + bv[1]);
        o[2] = (_Float16)(accT[T][2] + bv[2]);
        o[3] = (_Float16)(accT[T][3] + bv[3]);
        *((half4*)(hb + (size_t)(T * 16 + col) * 64)) = o;
    }
}

// ---------------------------------------------------------------------------
// Full horizontal pass (fallback, r9 verbatim): prologue + gather in one.
// ---------------------------------------------------------------------------
__global__ __launch_bounds__(256, 8) void deform_h_full_kernel(
    const float* __restrict__ x, const _Float16* __restrict__ xT,
    const float* __restrict__ wOffAll,
    const float* __restrict__ b_off_h, const float* __restrict__ b_mask_h,
    const float* __restrict__ b_off_v, const float* __restrict__ b_mask_v,
    const _Float16* __restrict__ wF16, const float* __restrict__ bias,
    float* __restrict__ off_v, float* __restrict__ mask_v,
    _Float16* __restrict__ x_hT)
{
    __shared__ __align__(16) char smem[18432];
    float (*red)[18][64] = reinterpret_cast<float(*)[18][64]>(smem);
    float (*red0)[64]    = reinterpret_cast<float(*)[64]>(smem);
    _Float16 (*valT)[200] = reinterpret_cast<_Float16(*)[200]>(smem);

    int lane = threadIdx.x & 63;
    int wv   = threadIdx.x >> 6;
    int c0 = __builtin_amdgcn_readfirstlane(wv << 4);

    SWIZZLE_NP();

    PROLOGUE_STENCIL()

    #pragma unroll
    for (int o = 0; o < 18; ++o) red[wv][o][lane] = a[o];
    __syncthreads();

    for (int v = threadIdx.x; v < 18 * 64; v += 256) {
        int idx = v >> 6;
        int px  = v & 63;
        float sum = red[0][idx][px] + red[1][idx][px]
                  + red[2][idx][px] + red[3][idx][px];
        int pixg = m * 64 + px;
        if (idx < 6) {
            red[0][idx][px] = sum + b_off_h[idx];
        } else if (idx < 9) {
            red[0][idx][px] = 1.f / (1.f + __expf(-(sum + b_mask_h[idx - 6])));
        } else if (idx < 15) {
            off_v[((size_t)n * 6 + (idx - 9)) * HW_ + pixg] = sum + b_off_v[idx - 9];
        } else {
            mask_v[((size_t)n * 3 + (idx - 15)) * HW_ + pixg] =
                1.f / (1.f + __expf(-(sum + b_mask_v[idx - 15])));
        }
    }
    __syncthreads();

    TAP_WAVE48(red0[2*k][p], red0[2*k + 1][p], red0[6 + k][p], 0, (k - 1))
    __syncthreads();   // tap reads of red0 done before valT overwrites

    const _Float16* sT = xT + (size_t)n * (HW_ * 64);
    GATHER_MFMA_BODY(sT)

    int orow = c0 + ((lane >> 4) << 2);
    floatx4 bv = *((const floatx4*)&bias[orow]);
    _Float16* hb = x_hT + ((size_t)n * HW_ + (size_t)m * 64) * 64 + orow;
    #pragma unroll
    for (int T = 0; T < 4; ++T) {
        half4 o;
        o[0] = (_Float16)(accT[T][0] + bv[0]);
        o[1] = (_Float16)(accT[T][1] + bv[1]);
        o[2] = (_Float16)(accT[T][2] + bv[2]);
        o[3] = (_Float16)(accT[T][3] + bv[3]);
        *((half4*)(hb + (size_t)(T * 16 + col) * 64)) = o;
    }
}

// ---------------------------------------------------------------------------
// Vertical pass (r9 verbatim): taps from off_v/mask_v, gathers from x_hT,
// NCHW f32 nt-store epilogue.
// ---------------------------------------------------------------------------
__global__ __launch_bounds__(256, 8) void deform_v_kernel(
    const _Float16* __restrict__ srcT, const float* __restrict__ off,
    const float* __restrict__ mask, const _Float16* __restrict__ wF16,
    const float* __restrict__ bias, float* __restrict__ out)
{
    __shared__ __align__(16) _Float16 valT[32][200];   // 12800 B

    int lane = threadIdx.x & 63;
    int wv   = threadIdx.x >> 6;
    int c0 = __builtin_amdgcn_readfirstlane(wv << 4);

    int bid = blockIdx.x;
    int n   = bid & 7;
    int m   = bid >> 3;

    TAP_WAVE48(off[(((size_t)n * 3 + k) * 2 + 0) * HW_ + pixp],
               off[(((size_t)n * 3 + k) * 2 + 1) * HW_ + pixp],
               mask[((size_t)n * 3 + k) * HW_ + pixp], (k - 1), 0)

    const _Float16* sT = srcT + (size_t)n * (HW_ * 64);
    GATHER_MFMA_BODY(sT)

    int orow = c0 + ((lane >> 4) << 2);
    floatx4 bv = *((const floatx4*)&bias[orow]);
    float* ob = out + ((size_t)n * C_ + orow) * HW_ + m * 64 + col;
    #pragma unroll
    for (int T = 0; T < 4; ++T) {
        __builtin_nontemporal_store(accT[T][0] + bv[0], &ob[T * 16 + (size_t)0 * HW_]);
        __builtin_nontemporal_store(accT[T][1] + bv[1], &ob[T * 16 + (size_t)1 * HW_]);
        __builtin_nontemporal_store(accT[T][2] + bv[2], &ob[T * 16 + (size_t)2 * HW_]);
        __builtin_nontemporal_store(accT[T][3] + bv[3], &ob[T * 16 + (size_t)3 * HW_]);
    }
}

// ---------------------------------------------------------------------------
extern "C" void kernel_launch(void* const* d_in, const int* in_sizes, int n_in,
                              void* d_out, int out_size, void* d_ws, size_t ws_size,
                              hipStream_t stream)
{
    const float* x        = (const float*)d_in[0];
    const float* w_off_h  = (const float*)d_in[1];
    const float* b_off_h  = (const float*)d_in[2];
    const float* w_mask_h = (const float*)d_in[3];
    const float* b_mask_h = (const float*)d_in[4];
    const float* w_off_v  = (const float*)d_in[5];
    const float* b_off_v  = (const float*)d_in[6];
    const float* w_mask_v = (const float*)d_in[7];
    const float* b_mask_v = (const float*)d_in[8];
    const float* w_h      = (const float*)d_in[9];
    const float* b_h      = (const float*)d_in[10];
    const float* w_v      = (const float*)d_in[11];
    const float* b_v      = (const float*)d_in[12];

    float* ws      = (float*)d_ws;
    float* off_v   = ws;                    // 786432 f32
    float* mask_v  = off_v  + 786432;       // 393216 f32

    dim3 grid(NPIX / 64), block(256);

    // big layout: + off_h (786432) + mask_h (393216) f32 -> needs ~41.1 MB
    size_t need_big = (size_t)(786432 + 393216) * 2 * 4 + 3584 * 4
                    + (size_t)(8388608 * 2 + 12288 * 2) * 2;

    if (ws_size >= need_big) {
        float* off_h   = mask_v + 393216;       // 786432 f32
        float* mask_h  = off_h  + 786432;       // 393216 f32
        float* wOffAll = mask_h + 393216;       // 3584 f32
        _Float16* xT     = (_Float16*)(wOffAll + 3584);   // 8388608 f16
        _Float16* x_hT   = xT + 8388608;                  // 8388608 f16
        _Float16* wF16_h = x_hT + 8388608;                // 12288 f16
        _Float16* wF16_v = wF16_h + 12288;                // 12288 f16

        prep_kernel<<<110, 256, 0, stream>>>(
            w_off_h, w_mask_h, w_off_v, w_mask_v, w_h, w_v,
            wOffAll, wF16_h, wF16_v);

        setup_big_kernel<<<grid, block, 0, stream>>>(
            x, xT, wOffAll, b_off_h, b_mask_h, b_off_v, b_mask_v,
            off_h, mask_h, off_v, mask_v);

        deform_h_slim_kernel<<<grid, block, 0, stream>>>(
            xT, off_h, mask_h, wF16_h, b_h, x_hT);

        deform_v_kernel<<<grid, block, 0, stream>>>(
            x_hT, off_v, mask_v, wF16_v, b_v, (float*)d_out);
    } else {
        // fallback: r9 layout + r9 kernels
        float* wOffAll = mask_v + 393216;       // 3584 f32
        _Float16* xT     = (_Float16*)(wOffAll + 3584);   // 8388608 f16
        _Float16* x_hT   = xT + 8388608;                  // 8388608 f16
        _Float16* wF16_h = x_hT + 8388608;                // 12288 f16
        _Float16* wF16_v = wF16_h + 12288;                // 12288 f16

        prep_kernel<<<110, 256, 0, stream>>>(
            w_off_h, w_mask_h, w_off_v, w_mask_v, w_h, w_v,
            wOffAll, wF16_h, wF16_v);

        transpose_kernel<<<grid, block, 0, stream>>>(x, xT);

        deform_h_full_kernel<<<grid, block, 0, stream>>>(
            x, xT, wOffAll, b_off_h, b_mask_h, b_off_v, b_mask_v,
            wF16_h, b_h, off_v, mask_v, x_hT);

        deform_v_kernel<<<grid, block, 0, stream>>>(
            x_hT, off_v, mask_v, wF16_v, b_v, (float*)d_out);
    }
}

// Round 11
// 178.219 us; speedup vs baseline: 1.1215x; 1.0533x over previous
//
#include <hip/hip_runtime.h>

#define C_ 64
#define H_ 128
#define W_ 128
#define B_ 8
#define HW_ (H_*W_)
#define NPIX (B_*HW_)

typedef _Float16 half8 __attribute__((ext_vector_type(8)));
typedef _Float16 half4 __attribute__((ext_vector_type(4)));
typedef float floatx4 __attribute__((ext_vector_type(4)));

// readlane helpers (compile-time lane index)
#define RDL_I(v, l) __builtin_amdgcn_readlane((v), (l))
#define RDL_F(v, l) __builtin_bit_cast(float, \
    __builtin_amdgcn_readlane(__builtin_bit_cast(int, (v)), (l)))

// ---------------------------------------------------------------------------
// Prep: wOffAll[c][56] packed f32 offset/mask weights + deform weights f16
// in K' = k*64 + c layout (matches conflict-free valT writes). 110 blocks.
// (Kept as its own launch: setup reads wOffAll, so fusing would race.)
// ---------------------------------------------------------------------------
__global__ __launch_bounds__(256) void prep_kernel(
    const float* __restrict__ w_off_h, const float* __restrict__ w_mask_h,
    const float* __restrict__ w_off_v, const float* __restrict__ w_mask_v,
    const float* __restrict__ w_h, const float* __restrict__ w_v,
    float* __restrict__ wOffAll, _Float16* __restrict__ wF16_h,
    _Float16* __restrict__ wF16_v)
{
    int gid = blockIdx.x * 256 + threadIdx.x;
    if (gid < 64 * 56) {
        int c = gid / 56, idx = gid - 56 * c;
        float v = 0.f;
        if (idx < 18)      v = w_off_h [((idx      ) / 3) * 192 + c * 3 + (idx      ) % 3];
        else if (idx < 27) v = w_mask_h[((idx - 18) / 3) * 192 + c * 3 + (idx - 18) % 3];
        else if (idx < 45) v = w_off_v [((idx - 27) / 3) * 192 + c * 3 + (idx - 27) % 3];
        else if (idx < 54) v = w_mask_v[((idx - 45) / 3) * 192 + c * 3 + (idx - 45) % 3];
        wOffAll[c * 56 + idx] = v;
    } else if (gid < 3584 + 24576) {
        int i = gid - 3584;
        if (i < 12288) {
            int o = i / 192, rem = i - o * 192;
            int c = rem / 3, k = rem - 3 * c;
            wF16_h[o * 192 + k * 64 + c] = (_Float16)w_h[i];
        } else {
            i -= 12288;
            int o = i / 192, rem = i - o * 192;
            int c = rem / 3, k = rem - 3 * c;
            wF16_v[o * 192 + k * 64 + c] = (_Float16)w_v[i];
        }
    }
}

// XCD-aware swizzle: one image (n) pinned to XCD n (bid&7).
#define SWIZZLE_NP()                        \
    int bid = blockIdx.x;                   \
    int n   = bid & 7;                      \
    int m   = bid >> 3;      /* 0..255 in-image tile */ \
    int pix = m * 64 + lane;                \
    int j = pix & (W_ - 1);                 \
    int i = pix >> 7;

// ---------------------------------------------------------------------------
// Round-11: setup = SINGLE-PASS transpose + prologue. The transpose's center
// read x[c][pix] IS the stencil's xc — load once, feed both. Removes one full
// 33.5 MB pass over x vs r10. Arithmetic identical (stencil consumes the f32
// register; tile stores the f16 cast, as before).
// smem: tile[64][66] f16 (8448 B, bytes 0..8448) -> transpose-out reads ->
//       red[4][18][64] f32 (18432 B, overwrites) -> reduce/scatter.
// ---------------------------------------------------------------------------
__global__ __launch_bounds__(256, 8) void setup_big_kernel(
    const float* __restrict__ x, _Float16* __restrict__ xT,
    const float* __restrict__ wOffAll,
    const float* __restrict__ b_off_h, const float* __restrict__ b_mask_h,
    const float* __restrict__ b_off_v, const float* __restrict__ b_mask_v,
    float* __restrict__ off_h, float* __restrict__ mask_h,
    float* __restrict__ off_v, float* __restrict__ mask_v)
{
    __shared__ __align__(16) char smem[18432];
    _Float16 (*tile)[66] = reinterpret_cast<_Float16(*)[66]>(smem);
    float (*red)[18][64] = reinterpret_cast<float(*)[18][64]>(smem);

    int lane = threadIdx.x & 63;
    int wv   = threadIdx.x >> 6;
    int c0 = __builtin_amdgcn_readfirstlane(wv << 4);

    SWIZZLE_NP();

    // ---- merged pass: stencil accumulate + tile fill (x read ONCE) ----
    float a[18];
    #pragma unroll
    for (int o = 0; o < 18; ++o) a[o] = 0.f;

    const float* xs = x + (size_t)n * C_ * HW_ + (size_t)c0 * HW_;
    for (int cc = 0; cc < 16; ++cc) {
        const float* s = xs + cc * HW_;
        float xc = s[pix];
        float xl = (j > 0)      ? s[pix - 1]  : 0.f;
        float xr = (j < W_ - 1) ? s[pix + 1]  : 0.f;
        float xu = (i > 0)      ? s[pix - W_] : 0.f;
        float xd2 = (i < H_ - 1) ? s[pix + W_] : 0.f;
        tile[c0 + cc][lane] = (_Float16)xc;          // transpose side-effect
        const float* wc = wOffAll + (c0 + cc) * 56;  // uniform -> s_load
        #pragma unroll
        for (int o = 0; o < 6; ++o) {
            a[o]   = fmaf(xl, wc[3*o],    fmaf(xc, wc[3*o+1],    fmaf(xr, wc[3*o+2],    a[o])));
            a[9+o] = fmaf(xu, wc[27+3*o], fmaf(xc, wc[27+3*o+1], fmaf(xd2, wc[27+3*o+2], a[9+o])));
        }
        #pragma unroll
        for (int o = 0; o < 3; ++o) {
            a[6+o]  = fmaf(xl, wc[18+3*o], fmaf(xc, wc[18+3*o+1], fmaf(xr, wc[18+3*o+2], a[6+o])));
            a[15+o] = fmaf(xu, wc[45+3*o], fmaf(xc, wc[45+3*o+1], fmaf(xd2, wc[45+3*o+2], a[15+o])));
        }
    }
    __syncthreads();

    // ---- transpose-out: NHWC f16 ----
    _Float16* xd = xT + ((size_t)n * HW_ + (size_t)m * 64) * 64;
    #pragma unroll
    for (int pp = 0; pp < 16; ++pp) {
        int p = wv * 16 + pp;
        xd[(size_t)p * 64 + lane] = tile[lane][p];
    }
    __syncthreads();            // tile dead before red overwrites

    // ---- cross-wave reduce + scatter: all 18 planes -> ws ----
    #pragma unroll
    for (int o = 0; o < 18; ++o) red[wv][o][lane] = a[o];
    __syncthreads();

    for (int v = threadIdx.x; v < 18 * 64; v += 256) {
        int idx = v >> 6;
        int px  = v & 63;
        float sum = red[0][idx][px] + red[1][idx][px]
                  + red[2][idx][px] + red[3][idx][px];
        int pixg = m * 64 + px;
        if (idx < 6) {
            off_h[((size_t)n * 6 + idx) * HW_ + pixg] = sum + b_off_h[idx];
        } else if (idx < 9) {
            mask_h[((size_t)n * 3 + (idx - 6)) * HW_ + pixg] =
                1.f / (1.f + __expf(-(sum + b_mask_h[idx - 6])));
        } else if (idx < 15) {
            off_v[((size_t)n * 6 + (idx - 9)) * HW_ + pixg] = sum + b_off_v[idx - 9];
        } else {
            mask_v[((size_t)n * 3 + (idx - 15)) * HW_ + pixg] =
                1.f / (1.f + __expf(-(sum + b_mask_v[idx - 15])));
        }
    }
}

// Fallback path: transpose only (ws too small for the off_h handoff).
__global__ __launch_bounds__(256, 8) void transpose_kernel(
    const float* __restrict__ x, _Float16* __restrict__ xT)
{
    __shared__ _Float16 tile[64][66];
    int lane = threadIdx.x & 63;
    int wv   = threadIdx.x >> 6;
    int bid = blockIdx.x;
    int n = bid & 7;
    int m = bid >> 3;
    const float* xs_t = x + (size_t)n * C_ * HW_ + (size_t)m * 64;
    #pragma unroll
    for (int cc = 0; cc < 16; ++cc) {
        int c = wv * 16 + cc;
        tile[c][lane] = (_Float16)xs_t[(size_t)c * HW_ + lane];
    }
    __syncthreads();
    _Float16* xd = xT + ((size_t)n * HW_ + (size_t)m * 64) * 64;
    #pragma unroll
    for (int pp = 0; pp < 16; ++pp) {
        int p = wv * 16 + pp;
        xd[(size_t)p * 64 + lane] = tile[lane][p];
    }
}

// r6-verified VALU prologue (fallback h only).
#define PROLOGUE_STENCIL()                                                    \
    float a[18];                                                              \
    _Pragma("unroll")                                                         \
    for (int o = 0; o < 18; ++o) a[o] = 0.f;                                  \
    {                                                                         \
        const float* xs = x + (size_t)n * C_ * HW_ + (size_t)c0 * HW_;        \
        for (int cc = 0; cc < 16; ++cc) {                                     \
            const float* s = xs + cc * HW_;                                   \
            float xc = s[pix];                                                \
            float xl = (j > 0)      ? s[pix - 1]  : 0.f;                      \
            float xr = (j < W_ - 1) ? s[pix + 1]  : 0.f;                      \
            float xu = (i > 0)      ? s[pix - W_] : 0.f;                      \
            float xd2 = (i < H_ - 1) ? s[pix + W_] : 0.f;                     \
            const float* wc = wOffAll + (c0 + cc) * 56;                       \
            _Pragma("unroll")                                                 \
            for (int o = 0; o < 6; ++o) {                                     \
                a[o]   = fmaf(xl, wc[3*o],    fmaf(xc, wc[3*o+1],    fmaf(xr, wc[3*o+2],    a[o])));    \
                a[9+o] = fmaf(xu, wc[27+3*o], fmaf(xc, wc[27+3*o+1], fmaf(xd2, wc[27+3*o+2], a[9+o]))); \
            }                                                                 \
            _Pragma("unroll")                                                 \
            for (int o = 0; o < 3; ++o) {                                     \
                a[6+o]  = fmaf(xl, wc[18+3*o], fmaf(xc, wc[18+3*o+1], fmaf(xr, wc[18+3*o+2], a[6+o])));    \
                a[15+o] = fmaf(xu, wc[45+3*o], fmaf(xc, wc[45+3*o+1], fmaf(xd2, wc[45+3*o+2], a[15+o]))); \
            }                                                                 \
        }                                                                     \
    }

// ---------------------------------------------------------------------------
// Per-wave tap compute in lanes 0..47 (r9-verified): results in registers,
// read back in the gather via v_readlane at compile-time lane indices.
// ---------------------------------------------------------------------------
#define TAP_WAVE48(DYE, DXE, MME, KYO, KXO)                                   \
    int   tI  = 0;                                                            \
    float tw0 = 0.f, tw1 = 0.f, tw2 = 0.f, tw3 = 0.f;                         \
    {                                                                         \
        int li = lane / 3, k = lane - 3 * li;                                 \
        if (lane < 48) {                                                      \
            int p = (li < 8) ? (wv * 8 + li) : (32 + wv * 8 + (li - 8));      \
            int pixp = m * 64 + p;                                            \
            float dy = (DYE);                                                 \
            float dx = (DXE);                                                 \
            float mm = (MME);                                                 \
            float fi = (float)(pixp >> 7), fj = (float)(pixp & (W_ - 1));     \
            float py = fi + (float)(KYO) + dy;                                \
            float px = fj + (float)(KXO) + dx;                                \
            float y0f = floorf(py), x0f = floorf(px);                         \
            float wy = py - y0f, wx = px - x0f;                               \
            int y0 = (int)y0f, x0 = (int)x0f;                                 \
            int y1 = y0 + 1, x1 = x0 + 1;                                     \
            bool vy0 = (y0 >= 0) && (y0 < H_);                                \
            bool vy1 = (y1 >= 0) && (y1 < H_);                                \
            bool vx0 = (x0 >= 0) && (x0 < W_);                                \
            bool vx1 = (x1 >= 0) && (x1 < W_);                                \
            float wy1 = 1.f - wy, wx1 = 1.f - wx;                             \
            float w00 = (vy0 && vx0) ? wy1 * wx1 * mm : 0.f;                  \
            float w01 = (vy0 && vx1) ? wy1 * wx  * mm : 0.f;                  \
            float w10 = (vy1 && vx0) ? wy  * wx1 * mm : 0.f;                  \
            float w11 = (vy1 && vx1) ? wy  * wx  * mm : 0.f;                  \
            int y0c = min(max(y0, 0), H_ - 1), y1c = min(max(y1, 0), H_ - 1); \
            int x0c = min(max(x0, 0), W_ - 1), x1c = min(max(x1, 0), W_ - 1); \
            int yb = min(max(y0, 0), H_ - 2),  xb = min(max(x0, 0), W_ - 2);  \
            int r0 = y0c - yb, r1 = y1c - yb;   /* in {0,1} */                \
            int cA = x0c - xb, cB = x1c - xb;   /* in {0,1} */                \
            tw0 = ((r0==0)&&(cA==0)?w00:0.f) + ((r0==0)&&(cB==0)?w01:0.f)     \
                + ((r1==0)&&(cA==0)?w10:0.f) + ((r1==0)&&(cB==0)?w11:0.f);    \
            tw1 = ((r0==0)&&(cA==1)?w00:0.f) + ((r0==0)&&(cB==1)?w01:0.f)     \
                + ((r1==0)&&(cA==1)?w10:0.f) + ((r1==0)&&(cB==1)?w11:0.f);    \
            tw2 = ((r0==1)&&(cA==0)?w00:0.f) + ((r0==1)&&(cB==0)?w01:0.f)     \
                + ((r1==1)&&(cA==0)?w10:0.f) + ((r1==1)&&(cB==0)?w11:0.f);    \
            tw3 = ((r0==1)&&(cA==1)?w00:0.f) + ((r0==1)&&(cB==1)?w01:0.f)     \
                + ((r1==1)&&(cA==1)?w10:0.f) + ((r1==1)&&(cB==1)?w11:0.f);    \
            tI = (yb * W_ + xb) * 64;                                         \
        }                                                                     \
    }

// NHWC gather + MFMA over two 32-pixel halves. Round-11: A-fragments
// (loop-invariant) hoisted ABOVE the hf loop — off the first-MFMA critical
// path and loaded once instead of twice.
#define GATHER_MFMA_BODY(ST)                                                  \
    int col = lane & 15;                                                      \
    const _Float16* wpA = wF16 + (size_t)(c0 + (lane & 15)) * 192             \
                        + ((lane >> 4) << 3);                                 \
    half8 A0 = *((const half8*)(wpA +   0));                                  \
    half8 A1 = *((const half8*)(wpA +  32));                                  \
    half8 A2 = *((const half8*)(wpA +  64));                                  \
    half8 A3 = *((const half8*)(wpA +  96));                                  \
    half8 A4 = *((const half8*)(wpA + 128));                                  \
    half8 A5 = *((const half8*)(wpA + 160));                                  \
    floatx4 accT[4];                                                          \
    _Pragma("unroll")                                                         \
    for (int T = 0; T < 4; ++T) accT[T] = floatx4{0.f, 0.f, 0.f, 0.f};        \
    _Pragma("unroll")                                                         \
    for (int hf = 0; hf < 2; ++hf) {                                          \
        _Pragma("unroll")                                                     \
        for (int q = 0; q < 8; ++q) {                                         \
            int r = wv * 8 + q;                                               \
            _Pragma("unroll")                                                 \
            for (int k = 0; k < 3; ++k) {                                     \
                const int tl = (hf * 8 + q) * 3 + k;                          \
                int ex   = RDL_I(tI, tl);                                     \
                float w0 = RDL_F(tw0, tl);                                    \
                float w1 = RDL_F(tw1, tl);                                    \
                float w2 = RDL_F(tw2, tl);                                    \
                float w3 = RDL_F(tw3, tl);                                    \
                const _Float16* cb = (ST) + ex;                               \
                float v00 = (float)cb[lane];                                  \
                float v01 = (float)cb[lane + 64];                             \
                float v10 = (float)cb[lane + 64 * W_];                        \
                float v11 = (float)cb[lane + 64 * W_ + 64];                   \
                float v = fmaf(w0, v00, fmaf(w1, v01,                         \
                          fmaf(w2, v10, w3 * v11)));                          \
                valT[r][k * 64 + lane] = (_Float16)v;                         \
            }                                                                 \
        }                                                                     \
        __syncthreads();                                                      \
        _Pragma("unroll")                                                     \
        for (int tt = 0; tt < 2; ++tt) {                                      \
            int T = hf * 2 + tt;                                              \
            const _Float16* bp = &valT[tt * 16 + col][(lane >> 4) << 3];      \
            floatx4 acc = accT[T];                                            \
            acc = __builtin_amdgcn_mfma_f32_16x16x32_f16(A0, *((const half8*)(bp +   0)), acc, 0, 0, 0); \
            acc = __builtin_amdgcn_mfma_f32_16x16x32_f16(A1, *((const half8*)(bp +  32)), acc, 0, 0, 0); \
            acc = __builtin_amdgcn_mfma_f32_16x16x32_f16(A2, *((const half8*)(bp +  64)), acc, 0, 0, 0); \
            acc = __builtin_amdgcn_mfma_f32_16x16x32_f16(A3, *((const half8*)(bp +  96)), acc, 0, 0, 0); \
            acc = __builtin_amdgcn_mfma_f32_16x16x32_f16(A4, *((const half8*)(bp + 128)), acc, 0, 0, 0); \
            acc = __builtin_amdgcn_mfma_f32_16x16x32_f16(A5, *((const half8*)(bp + 160)), acc, 0, 0, 0); \
            accT[T] = acc;                                                    \
        }                                                                     \
        if (hf == 0) __syncthreads();                                         \
    }

// ---------------------------------------------------------------------------
// Slim horizontal pass (big-ws path): taps from precomputed off_h/mask_h,
// NHWC gathers from xT, NHWC f16 output.
// ---------------------------------------------------------------------------
__global__ __launch_bounds__(256, 8) void deform_h_slim_kernel(
    const _Float16* __restrict__ srcT, const float* __restrict__ off,
    const float* __restrict__ mask, const _Float16* __restrict__ wF16,
    const float* __restrict__ bias, _Float16* __restrict__ x_hT)
{
    __shared__ __align__(16) _Float16 valT[32][200];   // 12800 B

    int lane = threadIdx.x & 63;
    int wv   = threadIdx.x >> 6;
    int c0 = __builtin_amdgcn_readfirstlane(wv << 4);

    int bid = blockIdx.x;
    int n   = bid & 7;
    int m   = bid >> 3;

    TAP_WAVE48(off[(((size_t)n * 3 + k) * 2 + 0) * HW_ + pixp],
               off[(((size_t)n * 3 + k) * 2 + 1) * HW_ + pixp],
               mask[((size_t)n * 3 + k) * HW_ + pixp], 0, (k - 1))

    const _Float16* sT = srcT + (size_t)n * (HW_ * 64);
    GATHER_MFMA_BODY(sT)

    int orow = c0 + ((lane >> 4) << 2);
    floatx4 bv = *((const floatx4*)&bias[orow]);
    _Float16* hb = x_hT + ((size_t)n * HW_ + (size_t)m * 64) * 64 + orow;
    #pragma unroll
    for (int T = 0; T < 4; ++T) {
        half4 o;
        o[0] = (_Float16)(accT[T][0] + bv[0]);
        o[1] = (_Float16)(accT[T][1] + bv[1]);
        o[2] = (_Float16)(accT[T][2] + bv[2]);
        o[3] = (_Float16)(accT[T][3] + bv[3]);
        *((half4*)(hb + (size_t)(T * 16 + col) * 64)) = o;
    }
}

// ---------------------------------------------------------------------------
// Full horizontal pass (fallback): prologue + gather in one kernel.
// ---------------------------------------------------------------------------
__global__ __launch_bounds__(256, 8) void deform_h_full_kernel(
    const float* __restrict__ x, const _Float16* __restrict__ xT,
    const float* __restrict__ wOffAll,
    const float* __restrict__ b_off_h, const float* __restrict__ b_mask_h,
    const float* __restrict__ b_off_v, const float* __restrict__ b_mask_v,
    const _Float16* __restrict__ wF16, const float* __restrict__ bias,
    float* __restrict__ off_v, float* __restrict__ mask_v,
    _Float16* __restrict__ x_hT)
{
    __shared__ __align__(16) char smem[18432];
    float (*red)[18][64] = reinterpret_cast<float(*)[18][64]>(smem);
    float (*red0)[64]    = reinterpret_cast<float(*)[64]>(smem);
    _Float16 (*valT)[200] = reinterpret_cast<_Float16(*)[200]>(smem);

    int lane = threadIdx.x & 63;
    int wv   = threadIdx.x >> 6;
    int c0 = __builtin_amdgcn_readfirstlane(wv << 4);

    SWIZZLE_NP();

    PROLOGUE_STENCIL()

    #pragma unroll
    for (int o = 0; o < 18; ++o) red[wv][o][lane] = a[o];
    __syncthreads();

    for (int v = threadIdx.x; v < 18 * 64; v += 256) {
        int idx = v >> 6;
        int px  = v & 63;
        float sum = red[0][idx][px] + red[1][idx][px]
                  + red[2][idx][px] + red[3][idx][px];
        int pixg = m * 64 + px;
        if (idx < 6) {
            red[0][idx][px] = sum + b_off_h[idx];
        } else if (idx < 9) {
            red[0][idx][px] = 1.f / (1.f + __expf(-(sum + b_mask_h[idx - 6])));
        } else if (idx < 15) {
            off_v[((size_t)n * 6 + (idx - 9)) * HW_ + pixg] = sum + b_off_v[idx - 9];
        } else {
            mask_v[((size_t)n * 3 + (idx - 15)) * HW_ + pixg] =
                1.f / (1.f + __expf(-(sum + b_mask_v[idx - 15])));
        }
    }
    __syncthreads();

    TAP_WAVE48(red0[2*k][p], red0[2*k + 1][p], red0[6 + k][p], 0, (k - 1))
    __syncthreads();   // tap reads of red0 done before valT overwrites

    const _Float16* sT = xT + (size_t)n * (HW_ * 64);
    GATHER_MFMA_BODY(sT)

    int orow = c0 + ((lane >> 4) << 2);
    floatx4 bv = *((const floatx4*)&bias[orow]);
    _Float16* hb = x_hT + ((size_t)n * HW_ + (size_t)m * 64) * 64 + orow;
    #pragma unroll
    for (int T = 0; T < 4; ++T) {
        half4 o;
        o[0] = (_Float16)(accT[T][0] + bv[0]);
        o[1] = (_Float16)(accT[T][1] + bv[1]);
        o[2] = (_Float16)(accT[T][2] + bv[2]);
        o[3] = (_Float16)(accT[T][3] + bv[3]);
        *((half4*)(hb + (size_t)(T * 16 + col) * 64)) = o;
    }
}

// ---------------------------------------------------------------------------
// Vertical pass: taps from off_v/mask_v, gathers from x_hT, NCHW f32 out.
// ---------------------------------------------------------------------------
__global__ __launch_bounds__(256, 8) void deform_v_kernel(
    const _Float16* __restrict__ srcT, const float* __restrict__ off,
    const float* __restrict__ mask, const _Float16* __restrict__ wF16,
    const float* __restrict__ bias, float* __restrict__ out)
{
    __shared__ __align__(16) _Float16 valT[32][200];   // 12800 B

    int lane = threadIdx.x & 63;
    int wv   = threadIdx.x >> 6;
    int c0 = __builtin_amdgcn_readfirstlane(wv << 4);

    int bid = blockIdx.x;
    int n   = bid & 7;
    int m   = bid >> 3;

    TAP_WAVE48(off[(((size_t)n * 3 + k) * 2 + 0) * HW_ + pixp],
               off[(((size_t)n * 3 + k) * 2 + 1) * HW_ + pixp],
               mask[((size_t)n * 3 + k) * HW_ + pixp], (k - 1), 0)

    const _Float16* sT = srcT + (size_t)n * (HW_ * 64);
    GATHER_MFMA_BODY(sT)

    int orow = c0 + ((lane >> 4) << 2);
    floatx4 bv = *((const floatx4*)&bias[orow]);
    float* ob = out + ((size_t)n * C_ + orow) * HW_ + m * 64 + col;
    #pragma unroll
    for (int T = 0; T < 4; ++T) {
        __builtin_nontemporal_store(accT[T][0] + bv[0], &ob[T * 16 + (size_t)0 * HW_]);
        __builtin_nontemporal_store(accT[T][1] + bv[1], &ob[T * 16 + (size_t)1 * HW_]);
        __builtin_nontemporal_store(accT[T][2] + bv[2], &ob[T * 16 + (size_t)2 * HW_]);
        __builtin_nontemporal_store(accT[T][3] + bv[3], &ob[T * 16 + (size_t)3 * HW_]);
    }
}

// ---------------------------------------------------------------------------
extern "C" void kernel_launch(void* const* d_in, const int* in_sizes, int n_in,
                              void* d_out, int out_size, void* d_ws, size_t ws_size,
                              hipStream_t stream)
{
    const float* x        = (const float*)d_in[0];
    const float* w_off_h  = (const float*)d_in[1];
    const float* b_off_h  = (const float*)d_in[2];
    const float* w_mask_h = (const float*)d_in[3];
    const float* b_mask_h = (const float*)d_in[4];
    const float* w_off_v  = (const float*)d_in[5];
    const float* b_off_v  = (const float*)d_in[6];
    const float* w_mask_v = (const float*)d_in[7];
    const float* b_mask_v = (const float*)d_in[8];
    const float* w_h      = (const float*)d_in[9];
    const float* b_h      = (const float*)d_in[10];
    const float* w_v      = (const float*)d_in[11];
    const float* b_v      = (const float*)d_in[12];

    float* ws      = (float*)d_ws;
    float* off_v   = ws;                    // 786432 f32
    float* mask_v  = off_v  + 786432;       // 393216 f32

    dim3 grid(NPIX / 64), block(256);

    // big layout: + off_h (786432) + mask_h (393216) f32 -> needs ~41.1 MB
    size_t need_big = (size_t)(786432 + 393216) * 2 * 4 + 3584 * 4
                    + (size_t)(8388608 * 2 + 12288 * 2) * 2;

    if (ws_size >= need_big) {
        float* off_h   = mask_v + 393216;       // 786432 f32
        float* mask_h  = off_h  + 786432;       // 393216 f32
        float* wOffAll = mask_h + 393216;       // 3584 f32
        _Float16* xT     = (_Float16*)(wOffAll + 3584);   // 8388608 f16
        _Float16* x_hT   = xT + 8388608;                  // 8388608 f16
        _Float16* wF16_h = x_hT + 8388608;                // 12288 f16
        _Float16* wF16_v = wF16_h + 12288;                // 12288 f16

        prep_kernel<<<110, 256, 0, stream>>>(
            w_off_h, w_mask_h, w_off_v, w_mask_v, w_h, w_v,
            wOffAll, wF16_h, wF16_v);

        setup_big_kernel<<<grid, block, 0, stream>>>(
            x, xT, wOffAll, b_off_h, b_mask_h, b_off_v, b_mask_v,
            off_h, mask_h, off_v, mask_v);

        deform_h_slim_kernel<<<grid, block, 0, stream>>>(
            xT, off_h, mask_h, wF16_h, b_h, x_hT);

        deform_v_kernel<<<grid, block, 0, stream>>>(
            x_hT, off_v, mask_v, wF16_v, b_v, (float*)d_out);
    } else {
        // fallback: r9 layout + kernels
        float* wOffAll = mask_v + 393216;       // 3584 f32
        _Float16* xT     = (_Float16*)(wOffAll + 3584);   // 8388608 f16
        _Float16* x_hT   = xT + 8388608;                  // 8388608 f16
        _Float16* wF16_h = x_hT + 8388608;                // 12288 f16
        _Float16* wF16_v = wF16_h + 12288;                // 12288 f16

        prep_kernel<<<110, 256, 0, stream>>>(
            w_off_h, w_mask_h, w_off_v, w_mask_v, w_h, w_v,
            wOffAll, wF16_h, wF16_v);

        transpose_kernel<<<grid, block, 0, stream>>>(x, xT);

        deform_h_full_kernel<<<grid, block, 0, stream>>>(
            x, xT, wOffAll, b_off_h, b_mask_h, b_off_v, b_mask_v,
            wF16_h, b_h, off_v, mask_v, x_hT);

        deform_v_kernel<<<grid, block, 0, stream>>>(
            x_hT, off_v, mask_v, wF16_v, b_v, (float*)d_out);
    }
}